// Round 1
// baseline (1164.391 us; speedup 1.0000x reference)
//
#include <hip/hip_runtime.h>
#include <math.h>

// ---------------------------------------------------------------------------
// SlotAttention fused forward, fp32.
//   logits fold:  Wkq[b,hq,:] = 0.125 * sum_d q[b,h,qi,d] * Wk[h*64+d,:]
//   y fold:       updates[b,qi,e] = ( (yun + eps*xsum) / (colsum + eps*Nkv) ) . Wv[e,:]
// k, v, attn are never materialized in HBM.
// ---------------------------------------------------------------------------

#define NKV   4096
#define DD    256
#define HQN   32          // HEADS * N_Q
#define EPSR  1e-8f

// workspace layout (float offsets)
#define WS_WKQ    0                     // 32*32*256      = 262144
#define WS_YUN    262144                // 262144
#define WS_COLSUM 524288                // 1024
#define WS_XSUM   525312                // 8192
#define WS_UPD    533504                // 65536
#define WS_SLOT   599040                // 65536
#define WS_WQT    664576                // 65536
#define WS_WVT    730112                // 65536
#define WS_WIHT   795648                // 196608
#define WS_WHHT   992256                // 196608
#define WS_W1T    1188864               // 262144
#define WS_W2T    1451008               // 262144
// total 1713152 floats = 6.85 MB

#define SMEM_K2   (20096 * 4)           // 80384 bytes dynamic LDS for k_attn

// ---------------------------------------------------------------------------
// generic 32x32 tiled transpose: in[R][C] -> out[C][R]
__global__ __launch_bounds__(256) void k_tr(const float* __restrict__ in,
                                            float* __restrict__ out, int R, int C) {
    __shared__ float tile[32][33];
    int bx = blockIdx.x * 32, by = blockIdx.y * 32;
    int x = bx + threadIdx.x;
    for (int k = 0; k < 32; k += 8) {
        int y = by + threadIdx.y + k;
        if (x < C && y < R) tile[threadIdx.y + k][threadIdx.x] = in[(size_t)y * C + x];
    }
    __syncthreads();
    int r = by + threadIdx.x;
    for (int k = 0; k < 32; k += 8) {
        int c = bx + threadIdx.y + k;
        if (c < C && r < R) out[(size_t)c * R + r] = tile[threadIdx.x][threadIdx.y + k];
    }
}

__global__ __launch_bounds__(256) void k_copy(const float* __restrict__ in,
                                              float* __restrict__ out, int n) {
    int i = blockIdx.x * 256 + threadIdx.x;
    if (i < n) out[i] = in[i];
}

// ---------------------------------------------------------------------------
// Per-iteration slot prep (one block per batch):
//  - zero yun/colsum/xsum accumulators for this b
//  - s = LN(slots);  qfull = s @ Wq^T;  Wkq[hq,:] = 0.125 * sum_d qfull[qi,h*64+d]*Wk[h*64+d,:]
__global__ __launch_bounds__(256) void k_slotprep(
    const float* __restrict__ slots, const float* __restrict__ g_s, const float* __restrict__ b_s,
    const float* __restrict__ wqt, const float* __restrict__ wk,
    float* __restrict__ wkq_g, float* __restrict__ yun_g,
    float* __restrict__ colsum_g, float* __restrict__ xsum_g)
{
    __shared__ float s_lds[8 * 256];
    __shared__ float qf[8 * 256];
    const int t = threadIdx.x;
    const int b = blockIdx.x;
    const int lane = t & 63, w = t >> 6;

    // zero accumulators
    #pragma unroll
    for (int k = 0; k < 32; ++k) yun_g[(size_t)b * 8192 + k * 256 + t] = 0.f;
    if (t < 32) colsum_g[b * 32 + t] = 0.f;
    xsum_g[b * 256 + t] = 0.f;

    // LN(slots): wave w handles rows w and w+4
    for (int r = w; r < 8; r += 4) {
        const float4 v = ((const float4*)(slots + ((size_t)b * 8 + r) * 256))[lane];
        float s0 = v.x + v.y + v.z + v.w;
        float s1 = v.x * v.x + v.y * v.y + v.z * v.z + v.w * v.w;
        #pragma unroll
        for (int o = 32; o >= 1; o >>= 1) { s0 += __shfl_xor(s0, o, 64); s1 += __shfl_xor(s1, o, 64); }
        float m = s0 * (1.f / 256.f);
        float rs = rsqrtf(s1 * (1.f / 256.f) - m * m + 1e-5f);
        float4 gg = ((const float4*)g_s)[lane];
        float4 bb = ((const float4*)b_s)[lane];
        float4 nn;
        nn.x = (v.x - m) * rs * gg.x + bb.x;
        nn.y = (v.y - m) * rs * gg.y + bb.y;
        nn.z = (v.z - m) * rs * gg.z + bb.z;
        nn.w = (v.w - m) * rs * gg.w + bb.w;
        ((float4*)(s_lds + r * 256))[lane] = nn;
    }
    __syncthreads();

    // qfull[qi][e=t] = sum_j s[qi][j] * Wq[e][j]   (wqt[j][e] coalesced)
    {
        float a[8];
        #pragma unroll
        for (int qi = 0; qi < 8; ++qi) a[qi] = 0.f;
        for (int j = 0; j < 256; ++j) {
            float wv = wqt[j * 256 + t];
            #pragma unroll
            for (int qi = 0; qi < 8; ++qi) a[qi] = fmaf(s_lds[qi * 256 + j], wv, a[qi]);
        }
        #pragma unroll
        for (int qi = 0; qi < 8; ++qi) qf[qi * 256 + t] = a[qi];
    }
    __syncthreads();

    // Wkq[h*8+qi][j=t] = 0.125 * sum_d qf[qi][h*64+d] * Wk[h*64+d][t]
    for (int h = 0; h < 4; ++h) {
        float a[8];
        #pragma unroll
        for (int qi = 0; qi < 8; ++qi) a[qi] = 0.f;
        for (int d = 0; d < 64; ++d) {
            float wv = wk[(size_t)(h * 64 + d) * 256 + t];
            #pragma unroll
            for (int qi = 0; qi < 8; ++qi) a[qi] = fmaf(qf[qi * 256 + h * 64 + d], wv, a[qi]);
        }
        #pragma unroll
        for (int qi = 0; qi < 8; ++qi)
            wkq_g[((size_t)b * HQN + h * 8 + qi) * 256 + t] = 0.125f * a[qi];
    }
}

// ---------------------------------------------------------------------------
// Main fused pass. Per chunk of 64 tokens:
//  stage(raw inputs, XOR-swizzled) -> LN in LDS -> logits(32/token) ->
//  joint softmax(32) -> colsum partial (+vis write on last iter) ->
//  rank-32 y accumulation into registers.
// Block end: atomicAdd yun / xsum / colsum.
__global__ __launch_bounds__(256, 2) void k_attn(
    const float* __restrict__ inp, const float* __restrict__ gln, const float* __restrict__ bln,
    const float* __restrict__ wkq_g, float* __restrict__ yun_g, float* __restrict__ colsum_g,
    float* __restrict__ xsum_g, float* __restrict__ out_vis, float* __restrict__ out_temp,
    int write_vis)
{
    extern __shared__ float sm[];
    float4* x4  = (float4*)sm;       // 64 rows x 64 granules (16384 f)
    float* att   = sm + 16384;       // 64 x 36
    float* red   = sm + 18688;       // 64 x 8
    float* cpart = sm + 19200;       // 32 x 8
    float* gb    = sm + 19456;       // 2 x 256
    float* mrs   = sm + 19968;       // 64 x 2

    const int t = threadIdx.x;
    const int lane = t & 63;
    const int wave = t >> 6;
    const int b  = blockIdx.y;
    const int kb = blockIdx.x;
    const int hqb = __builtin_amdgcn_readfirstlane(wave) * 8;   // wave-uniform -> s_loads

    gb[t] = gln[t];
    gb[256 + t] = bln[t];

    float4 acc[8];
    #pragma unroll
    for (int u = 0; u < 8; ++u) acc[u] = make_float4(0.f, 0.f, 0.f, 0.f);
    float4 xsv = make_float4(0.f, 0.f, 0.f, 0.f);
    float csum = 0.f;

    const float4* inp4 = (const float4*)(inp + (size_t)b * NKV * DD);
    const float* wkqb  = wkq_g + (size_t)b * HQN * DD;

    for (int ci = 0; ci < 4; ++ci) {
        const int n0 = (kb + 16 * ci) * 64;

        // ---- stage 64 tokens (granule-XOR swizzled) ----
        #pragma unroll
        for (int k2 = 0; k2 < 16; ++k2) {
            int gi = t + k2 * 256;
            int tok = gi >> 6, g = gi & 63;
            x4[tok * 64 + (g ^ (tok & 7))] = inp4[(size_t)n0 * 64 + gi];
        }
        __syncthreads();

        // ---- LayerNorm in LDS ----
        {
            const int tok = lane, sw = tok & 7;
            float s0 = 0.f, s1 = 0.f;
            #pragma unroll
            for (int k2 = 0; k2 < 16; ++k2) {
                int g = wave * 16 + k2;
                float4 v = x4[tok * 64 + (g ^ sw)];
                s0 += v.x + v.y + v.z + v.w;
                s1 += v.x * v.x + v.y * v.y + v.z * v.z + v.w * v.w;
            }
            red[tok * 8 + wave] = s0;
            red[tok * 8 + 4 + wave] = s1;
            __syncthreads();
            if (t < 64) {
                float m  = (red[t*8] + red[t*8+1] + red[t*8+2] + red[t*8+3]) * (1.f / 256.f);
                float q2 = (red[t*8+4] + red[t*8+5] + red[t*8+6] + red[t*8+7]) * (1.f / 256.f);
                mrs[t * 2]     = m;
                mrs[t * 2 + 1] = rsqrtf(q2 - m * m + 1e-5f);
            }
            __syncthreads();
            const float m = mrs[tok * 2], rs = mrs[tok * 2 + 1];
            #pragma unroll
            for (int k2 = 0; k2 < 16; ++k2) {
                int g = wave * 16 + k2;
                int idx = tok * 64 + (g ^ sw);
                float4 v = x4[idx];
                int j = g * 4;
                float4 gg = *(const float4*)(gb + j);
                float4 bb = *(const float4*)(gb + 256 + j);
                v.x = (v.x - m) * rs * gg.x + bb.x;
                v.y = (v.y - m) * rs * gg.y + bb.y;
                v.z = (v.z - m) * rs * gg.z + bb.z;
                v.w = (v.w - m) * rs * gg.w + bb.w;
                x4[idx] = v;
            }
        }
        __syncthreads();

        // ---- logits + joint softmax over 32 (h,q) ----
        {
            const int tok = lane, sw = tok & 7;
            float lg[8];
            #pragma unroll
            for (int u = 0; u < 8; ++u) lg[u] = 0.f;
            #pragma unroll 2
            for (int j4 = 0; j4 < 64; ++j4) {
                float4 xv = x4[tok * 64 + (j4 ^ sw)];
                #pragma unroll
                for (int u = 0; u < 8; ++u) {
                    float4 wv = *(const float4*)(wkqb + (size_t)(hqb + u) * DD + j4 * 4);
                    lg[u] = fmaf(xv.x, wv.x, lg[u]);
                    lg[u] = fmaf(xv.y, wv.y, lg[u]);
                    lg[u] = fmaf(xv.z, wv.z, lg[u]);
                    lg[u] = fmaf(xv.w, wv.w, lg[u]);
                }
            }
            float pm = lg[0];
            #pragma unroll
            for (int u = 1; u < 8; ++u) pm = fmaxf(pm, lg[u]);
            red[tok * 8 + wave] = pm;
            __syncthreads();
            float mx = fmaxf(fmaxf(red[tok*8], red[tok*8+1]), fmaxf(red[tok*8+2], red[tok*8+3]));
            float ps = 0.f;
            float ex[8];
            #pragma unroll
            for (int u = 0; u < 8; ++u) { ex[u] = exp2f((lg[u] - mx) * 1.44269504f); ps += ex[u]; }
            red[tok * 8 + 4 + wave] = ps;
            __syncthreads();
            float inv = 1.f / (red[tok*8+4] + red[tok*8+5] + red[tok*8+6] + red[tok*8+7]);
            #pragma unroll
            for (int u = 0; u < 8; ++u) att[tok * 36 + hqb + u] = ex[u] * inv;
        }
        __syncthreads();

        // ---- colsum partials + attn_vis / attn_temp write (last iter only) ----
        {
            const int hq = t & 31, gq = t >> 5;
            float s = 0.f;
            #pragma unroll
            for (int k2 = 0; k2 < 8; ++k2) s += att[(gq * 8 + k2) * 36 + hq];
            cpart[hq * 8 + gq] = s;
            if (write_vis) {
                int tok = t >> 2, pr = t & 3;
                #pragma unroll
                for (int c = 0; c < 2; ++c) {
                    int q = pr * 2 + c;
                    float v = att[tok*36 + q] + att[tok*36 + 8 + q] +
                              att[tok*36 + 16 + q] + att[tok*36 + 24 + q];
                    size_t o = ((size_t)b * NKV + n0 + tok) * 8 + q;
                    out_vis[o]  = v;
                    out_temp[o] = v;
                }
            }
            __syncthreads();
            if (t < 32) {
                float s2 = 0.f;
                #pragma unroll
                for (int g = 0; g < 8; ++g) s2 += cpart[t * 8 + g];
                csum += s2;
            }
        }

        // ---- y accumulation: y[hq][j] += attn[tok][hq] * x[tok][j] ----
        {
            const int jq = lane;
            #pragma unroll 2
            for (int tok = 0; tok < 64; ++tok) {
                float4 xv = x4[tok * 64 + (jq ^ (tok & 7))];
                float4 a0 = *(const float4*)(att + tok * 36 + hqb);
                float4 a1 = *(const float4*)(att + tok * 36 + hqb + 4);
                float av[8] = {a0.x, a0.y, a0.z, a0.w, a1.x, a1.y, a1.z, a1.w};
                #pragma unroll
                for (int u = 0; u < 8; ++u) {
                    acc[u].x = fmaf(av[u], xv.x, acc[u].x);
                    acc[u].y = fmaf(av[u], xv.y, acc[u].y);
                    acc[u].z = fmaf(av[u], xv.z, acc[u].z);
                    acc[u].w = fmaf(av[u], xv.w, acc[u].w);
                }
                if (wave == 0) { xsv.x += xv.x; xsv.y += xv.y; xsv.z += xv.z; xsv.w += xv.w; }
            }
        }
        __syncthreads();
    }

    // ---- block reduction to global accumulators ----
    {
        const int jq = lane;
        #pragma unroll
        for (int u = 0; u < 8; ++u) {
            float* p = yun_g + ((size_t)b * HQN + hqb + u) * DD + jq * 4;
            atomicAdd(p + 0, acc[u].x);
            atomicAdd(p + 1, acc[u].y);
            atomicAdd(p + 2, acc[u].z);
            atomicAdd(p + 3, acc[u].w);
        }
        if (wave == 0) {
            float* p = xsum_g + (size_t)b * DD + jq * 4;
            atomicAdd(p + 0, xsv.x);
            atomicAdd(p + 1, xsv.y);
            atomicAdd(p + 2, xsv.z);
            atomicAdd(p + 3, xsv.w);
        }
        if (t < 32) atomicAdd(colsum_g + b * 32 + t, csum);
    }
}

// ---------------------------------------------------------------------------
// updates[b,qi,e] = ((yun[hq,:] + eps*xsum)/(colsum[hq]+eps*Nkv)) . Wv[e,:]
__global__ __launch_bounds__(256) void k_updates(
    const float* __restrict__ yun_g, const float* __restrict__ colsum_g,
    const float* __restrict__ xsum_g, const float* __restrict__ wvt,
    float* __restrict__ upd)
{
    __shared__ float y[HQN * DD];
    const int t = threadIdx.x;
    const int b = blockIdx.x;
    const float xs = xsum_g[b * DD + t];
    for (int hq = 0; hq < HQN; ++hq) {
        float S = colsum_g[b * 32 + hq] + EPSR * (float)NKV;
        y[hq * DD + t] = (yun_g[((size_t)b * HQN + hq) * DD + t] + EPSR * xs) / S;
    }
    __syncthreads();
    const int h = t >> 6;
    float a[8];
    #pragma unroll
    for (int qi = 0; qi < 8; ++qi) a[qi] = 0.f;
    for (int j = 0; j < 256; ++j) {
        float wv = wvt[j * DD + t];
        #pragma unroll
        for (int qi = 0; qi < 8; ++qi) a[qi] = fmaf(y[(h * 8 + qi) * DD + j], wv, a[qi]);
    }
    #pragma unroll
    for (int qi = 0; qi < 8; ++qi)
        upd[((size_t)b * 8 + qi) * DD + t] = a[qi];
}

// ---------------------------------------------------------------------------
// GRU cell + LN + MLP residual; 64 blocks of 4 slot-rows each.
__global__ __launch_bounds__(256) void k_gru_mlp(
    const float* __restrict__ upd, float* __restrict__ slots_cur,
    const float* __restrict__ wiht, const float* __restrict__ whht,
    const float* __restrict__ bih, const float* __restrict__ bhh,
    const float* __restrict__ gm, const float* __restrict__ bm,
    const float* __restrict__ w1t, const float* __restrict__ b1,
    const float* __restrict__ w2t, const float* __restrict__ b2,
    float* __restrict__ out_slots)
{
    __shared__ float u_l[4 * 256];   // updates, reused for m (LN output)
    __shared__ float sp_l[4 * 256];  // prev slots, reused for smid
    __shared__ float h1_l[4 * 1024];
    const int t = threadIdx.x;
    const int b = blockIdx.x >> 1;
    const int r0 = (blockIdx.x & 1) * 4;

    #pragma unroll
    for (int r = 0; r < 4; ++r) {
        u_l[r * 256 + t]  = upd[((size_t)b * 8 + r0 + r) * 256 + t];
        sp_l[r * 256 + t] = slots_cur[((size_t)b * 8 + r0 + r) * 256 + t];
    }
    __syncthreads();

    float gx[4][3], gh[4][3];
    #pragma unroll
    for (int r = 0; r < 4; ++r)
        #pragma unroll
        for (int g = 0; g < 3; ++g) { gx[r][g] = 0.f; gh[r][g] = 0.f; }
    for (int j = 0; j < 256; ++j) {
        float w0 = wiht[(size_t)j * 768 + t];
        float w1 = wiht[(size_t)j * 768 + 256 + t];
        float w2 = wiht[(size_t)j * 768 + 512 + t];
        float v0 = whht[(size_t)j * 768 + t];
        float v1 = whht[(size_t)j * 768 + 256 + t];
        float v2 = whht[(size_t)j * 768 + 512 + t];
        #pragma unroll
        for (int r = 0; r < 4; ++r) {
            float uv = u_l[r * 256 + j], sv = sp_l[r * 256 + j];
            gx[r][0] = fmaf(uv, w0, gx[r][0]);
            gx[r][1] = fmaf(uv, w1, gx[r][1]);
            gx[r][2] = fmaf(uv, w2, gx[r][2]);
            gh[r][0] = fmaf(sv, v0, gh[r][0]);
            gh[r][1] = fmaf(sv, v1, gh[r][1]);
            gh[r][2] = fmaf(sv, v2, gh[r][2]);
        }
    }
    __syncthreads();

    const float bi0 = bih[t], bi1 = bih[256 + t], bi2 = bih[512 + t];
    const float bh0 = bhh[t], bh1 = bhh[256 + t], bh2 = bhh[512 + t];
    #pragma unroll
    for (int r = 0; r < 4; ++r) {
        float rr = 1.f / (1.f + expf(-(gx[r][0] + bi0 + gh[r][0] + bh0)));
        float zz = 1.f / (1.f + expf(-(gx[r][1] + bi1 + gh[r][1] + bh1)));
        float nn = tanhf(gx[r][2] + bi2 + rr * (gh[r][2] + bh2));
        sp_l[r * 256 + t] = (1.f - zz) * nn + zz * sp_l[r * 256 + t];  // smid
    }
    __syncthreads();

    // LN per row (wave w handles row w), write m into u_l
    {
        const int w = t >> 6, lane = t & 63;
        float4 v = ((const float4*)(sp_l + w * 256))[lane];
        float s0 = v.x + v.y + v.z + v.w;
        float s1 = v.x * v.x + v.y * v.y + v.z * v.z + v.w * v.w;
        #pragma unroll
        for (int o = 32; o >= 1; o >>= 1) { s0 += __shfl_xor(s0, o, 64); s1 += __shfl_xor(s1, o, 64); }
        float m = s0 * (1.f / 256.f);
        float rs = rsqrtf(s1 * (1.f / 256.f) - m * m + 1e-5f);
        float4 gg = ((const float4*)gm)[lane];
        float4 bb = ((const float4*)bm)[lane];
        float4 nn;
        nn.x = (v.x - m) * rs * gg.x + bb.x;
        nn.y = (v.y - m) * rs * gg.y + bb.y;
        nn.z = (v.z - m) * rs * gg.z + bb.z;
        nn.w = (v.w - m) * rs * gg.w + bb.w;
        ((float4*)(u_l + w * 256))[lane] = nn;
    }
    __syncthreads();

    float h1a[4][4];
    #pragma unroll
    for (int r = 0; r < 4; ++r)
        #pragma unroll
        for (int g = 0; g < 4; ++g) h1a[r][g] = 0.f;
    for (int j = 0; j < 256; ++j) {
        float w0 = w1t[(size_t)j * 1024 + t];
        float w1 = w1t[(size_t)j * 1024 + 256 + t];
        float w2 = w1t[(size_t)j * 1024 + 512 + t];
        float w3 = w1t[(size_t)j * 1024 + 768 + t];
        #pragma unroll
        for (int r = 0; r < 4; ++r) {
            float mv = u_l[r * 256 + j];
            h1a[r][0] = fmaf(mv, w0, h1a[r][0]);
            h1a[r][1] = fmaf(mv, w1, h1a[r][1]);
            h1a[r][2] = fmaf(mv, w2, h1a[r][2]);
            h1a[r][3] = fmaf(mv, w3, h1a[r][3]);
        }
    }
    #pragma unroll
    for (int r = 0; r < 4; ++r)
        #pragma unroll
        for (int g = 0; g < 4; ++g)
            h1_l[r * 1024 + g * 256 + t] = fmaxf(h1a[r][g] + b1[g * 256 + t], 0.f);
    __syncthreads();

    float oa[4];
    #pragma unroll
    for (int r = 0; r < 4; ++r) oa[r] = 0.f;
    for (int k = 0; k < 1024; ++k) {
        float wv = w2t[(size_t)k * 256 + t];
        #pragma unroll
        for (int r = 0; r < 4; ++r) oa[r] = fmaf(h1_l[r * 1024 + k], wv, oa[r]);
    }
    const float bb2 = b2[t];
    #pragma unroll
    for (int r = 0; r < 4; ++r) {
        float res = sp_l[r * 256 + t] + oa[r] + bb2;
        size_t o = ((size_t)b * 8 + r0 + r) * 256 + t;
        slots_cur[o] = res;
        if (out_slots) out_slots[o] = res;
    }
}

// ---------------------------------------------------------------------------
extern "C" void kernel_launch(void* const* d_in, const int* in_sizes, int n_in,
                              void* d_out, int out_size, void* d_ws, size_t ws_size,
                              hipStream_t stream) {
    const float* inp    = (const float*)d_in[0];
    const float* slots0 = (const float*)d_in[1];
    const float* ln_in_g = (const float*)d_in[2];
    const float* ln_in_b = (const float*)d_in[3];
    const float* ln_s_g  = (const float*)d_in[4];
    const float* ln_s_b  = (const float*)d_in[5];
    const float* ln_m_g  = (const float*)d_in[6];
    const float* ln_m_b  = (const float*)d_in[7];
    const float* Wq  = (const float*)d_in[8];
    const float* Wk  = (const float*)d_in[9];
    const float* Wv  = (const float*)d_in[10];
    const float* Wih = (const float*)d_in[11];
    const float* Whh = (const float*)d_in[12];
    const float* bih = (const float*)d_in[13];
    const float* bhh = (const float*)d_in[14];
    const float* W1  = (const float*)d_in[15];
    const float* b1  = (const float*)d_in[16];
    const float* W2  = (const float*)d_in[17];
    const float* b2  = (const float*)d_in[18];

    float* ws = (float*)d_ws;
    float* wkq    = ws + WS_WKQ;
    float* yun    = ws + WS_YUN;
    float* colsum = ws + WS_COLSUM;
    float* xsum   = ws + WS_XSUM;
    float* upd    = ws + WS_UPD;
    float* slot   = ws + WS_SLOT;
    float* wqt    = ws + WS_WQT;
    float* wvt    = ws + WS_WVT;
    float* wiht   = ws + WS_WIHT;
    float* whht   = ws + WS_WHHT;
    float* w1t    = ws + WS_W1T;
    float* w2t    = ws + WS_W2T;

    float* out_slots = (float*)d_out;
    float* out_vis   = out_slots + 32 * 8 * 256;
    float* out_temp  = out_vis + 32 * 4096 * 8;

    (void)hipFuncSetAttribute((const void*)k_attn,
                              hipFuncAttributeMaxDynamicSharedMemorySize, SMEM_K2);

    dim3 tb(32, 8);
    k_tr<<<dim3(8, 8),  tb, 0, stream>>>(Wq,  wqt,  256, 256);
    k_tr<<<dim3(8, 8),  tb, 0, stream>>>(Wv,  wvt,  256, 256);
    k_tr<<<dim3(8, 24), tb, 0, stream>>>(Wih, wiht, 768, 256);
    k_tr<<<dim3(8, 24), tb, 0, stream>>>(Whh, whht, 768, 256);
    k_tr<<<dim3(8, 32), tb, 0, stream>>>(W1,  w1t,  1024, 256);
    k_tr<<<dim3(32, 8), tb, 0, stream>>>(W2,  w2t,  256, 1024);
    k_copy<<<256, 256, 0, stream>>>(slots0, slot, 65536);

    for (int it = 0; it < 3; ++it) {
        k_slotprep<<<32, 256, 0, stream>>>(slot, ln_s_g, ln_s_b, wqt, Wk,
                                           wkq, yun, colsum, xsum);
        k_attn<<<dim3(16, 32), 256, SMEM_K2, stream>>>(
            inp, ln_in_g, ln_in_b, wkq, yun, colsum, xsum,
            out_vis, out_temp, (it == 2) ? 1 : 0);
        k_updates<<<32, 256, 0, stream>>>(yun, colsum, xsum, wvt, upd);
        k_gru_mlp<<<64, 256, 0, stream>>>(upd, slot, wiht, whht, bih, bhh,
                                          ln_m_g, ln_m_b, w1t, b1, w2t, b2,
                                          (it == 2) ? out_slots : nullptr);
    }
}

// Round 2
// 990.542 us; speedup vs baseline: 1.1755x; 1.1755x over previous
//
#include <hip/hip_runtime.h>
#include <math.h>

// ---------------------------------------------------------------------------
// SlotAttention fused forward, fp32 attention path, bf16 GRU/MLP weights.
// LN(inputs) folded out:  logit = rs*dot(x_raw, w') - rs*m*c1 + c0
//   with w' = 0.125 * g_in (.) (q@Wk-combined), c1 = sum_j g_j*wkq_j, c0 = sum_j b_j*wkq_j
// y-side folds:  sum_t a*xn = g.(V - A1) + b.A0 ;  xsum = g.U - g.SM + N*b
//   V = sum a*rs*x_raw, A0 = sum a, A1 = sum a*rs*m, U = sum rs*x, SM = sum rs*m
// ---------------------------------------------------------------------------

#define NKV   4096
#define DD    256
#define HQN   32
#define EPSR  1e-8f

// workspace layout (float offsets)
#define WS_V     0                      // 32*32*256 = 262144
#define WS_WP    262144                 // 262144
#define WS_A0    524288                 // 1024
#define WS_A1    525312                 // 1024
#define WS_U     526336                 // 8192
#define WS_SM    534528                 // 32
#define WS_C0    534560                 // 1024
#define WS_C1    535584                 // 1024
#define WS_SLOT  536608                 // 65536
// bf16 weights start at byte offset 602144*4 = 2408576
#define WS_BF_BYTES 2408576
#define BF_WIH   0                      // 196608 elems = 393216 B
#define BF_WHH   393216
#define BF_W1    786432                 // 262144 elems = 524288 B
#define BF_W2    1310720
// bf16 end: 2408576 + 1835008 = 4243584 B (~4.05 MB total ws)

#define SMEM_ATTN (17856 * 4)           // 71424 bytes dynamic LDS

__device__ __forceinline__ float bflo(unsigned u) { return __uint_as_float(u << 16); }
__device__ __forceinline__ float bfhi(unsigned u) { return __uint_as_float(u & 0xffff0000u); }

__device__ __forceinline__ float dot8(uint4 w, float4 a, float4 b) {
    float s = 0.f;
    s = fmaf(bflo(w.x), a.x, s); s = fmaf(bfhi(w.x), a.y, s);
    s = fmaf(bflo(w.y), a.z, s); s = fmaf(bfhi(w.y), a.w, s);
    s = fmaf(bflo(w.z), b.x, s); s = fmaf(bfhi(w.z), b.y, s);
    s = fmaf(bflo(w.w), b.z, s); s = fmaf(bfhi(w.w), b.w, s);
    return s;
}

__global__ __launch_bounds__(256) void k_cvt(const float* __restrict__ in,
                                             unsigned short* __restrict__ out, int n) {
    int i = blockIdx.x * 256 + threadIdx.x;
    if (i < n) {
        unsigned x = __float_as_uint(in[i]);
        unsigned r = (x + 0x7fffu + ((x >> 16) & 1u)) >> 16;   // RNE
        out[i] = (unsigned short)r;
    }
}

__global__ __launch_bounds__(256) void k_copy(const float* __restrict__ in,
                                              float* __restrict__ out, int n) {
    int i = blockIdx.x * 256 + threadIdx.x;
    if (i < n) out[i] = in[i];
}

// ---------------------------------------------------------------------------
// Per-iteration slot prep (one block per batch):
//  zero accumulators; s = LN(slots); qf = s@Wq^T;
//  wkq[hq,:] = 0.125 * sum_d qf[qi,h*64+d]*Wk[h*64+d,:]
//  w' = wkq * g_in ; c1[hq] = sum w' ; c0[hq] = sum wkq*b_in
__global__ __launch_bounds__(256) void k_slotprep(
    const float* __restrict__ slots, const float* __restrict__ g_s, const float* __restrict__ b_s,
    const float* __restrict__ Wq, const float* __restrict__ Wk,
    const float* __restrict__ g_in, const float* __restrict__ b_in,
    float* __restrict__ wp_g, float* __restrict__ c0_g, float* __restrict__ c1_g,
    float* __restrict__ V_g, float* __restrict__ A0_g, float* __restrict__ A1_g,
    float* __restrict__ U_g, float* __restrict__ SM_g)
{
    __shared__ float s_lds[2048];
    __shared__ float qf[2048];
    __shared__ float redc[2048];
    const int t = threadIdx.x;
    const int b = blockIdx.x;
    const int lane = t & 63, w = t >> 6;

    // zero accumulators
    #pragma unroll
    for (int k = 0; k < 32; ++k) V_g[(size_t)b * 8192 + k * 256 + t] = 0.f;
    if (t < 32) { A0_g[b * 32 + t] = 0.f; A1_g[b * 32 + t] = 0.f; }
    U_g[b * 256 + t] = 0.f;
    if (t == 0) SM_g[b] = 0.f;

    // LN(slots)
    for (int r = w; r < 8; r += 4) {
        const float4 v = ((const float4*)(slots + ((size_t)b * 8 + r) * 256))[lane];
        float s0 = v.x + v.y + v.z + v.w;
        float s1 = v.x * v.x + v.y * v.y + v.z * v.z + v.w * v.w;
        #pragma unroll
        for (int o = 32; o >= 1; o >>= 1) { s0 += __shfl_xor(s0, o, 64); s1 += __shfl_xor(s1, o, 64); }
        float m = s0 * (1.f / 256.f);
        float rs = rsqrtf(s1 * (1.f / 256.f) - m * m + 1e-5f);
        float4 gg = ((const float4*)g_s)[lane];
        float4 bb = ((const float4*)b_s)[lane];
        float4 nn;
        nn.x = (v.x - m) * rs * gg.x + bb.x;
        nn.y = (v.y - m) * rs * gg.y + bb.y;
        nn.z = (v.z - m) * rs * gg.z + bb.z;
        nn.w = (v.w - m) * rs * gg.w + bb.w;
        ((float4*)(s_lds + r * 256))[lane] = nn;
    }
    __syncthreads();

    // qf[qi][e=t] = sum_j s[qi][j] * Wq[t][j]
    {
        float a[8];
        #pragma unroll
        for (int qi = 0; qi < 8; ++qi) a[qi] = 0.f;
        const float4* wq4 = (const float4*)Wq;
        for (int j4 = 0; j4 < 64; ++j4) {
            float4 wv = wq4[(size_t)t * 64 + j4];
            #pragma unroll
            for (int qi = 0; qi < 8; ++qi) {
                float4 sv = *(const float4*)(s_lds + qi * 256 + j4 * 4);
                a[qi] = fmaf(sv.x, wv.x, a[qi]);
                a[qi] = fmaf(sv.y, wv.y, a[qi]);
                a[qi] = fmaf(sv.z, wv.z, a[qi]);
                a[qi] = fmaf(sv.w, wv.w, a[qi]);
            }
        }
        #pragma unroll
        for (int qi = 0; qi < 8; ++qi) qf[qi * 256 + t] = a[qi];
    }
    __syncthreads();

    const float gv = g_in[t], bv = b_in[t];
    for (int h = 0; h < 4; ++h) {
        float a2[8];
        #pragma unroll
        for (int qi = 0; qi < 8; ++qi) a2[qi] = 0.f;
        for (int d = 0; d < 64; ++d) {
            float wv = Wk[(size_t)(h * 64 + d) * 256 + t];
            #pragma unroll
            for (int qi = 0; qi < 8; ++qi) a2[qi] = fmaf(qf[qi * 256 + h * 64 + d], wv, a2[qi]);
        }
        #pragma unroll
        for (int qi = 0; qi < 8; ++qi) {
            float kv = 0.125f * a2[qi];
            wp_g[((size_t)b * HQN + h * 8 + qi) * 256 + t] = kv * gv;
            redc[qi * 256 + t] = kv * gv;
        }
        __syncthreads();
        // reduce c1 rows: wave w handles rows 2w, 2w+1
        #pragma unroll
        for (int rep = 0; rep < 2; ++rep) {
            int r = w * 2 + rep;
            float sv = redc[r * 256 + lane] + redc[r * 256 + 64 + lane] +
                       redc[r * 256 + 128 + lane] + redc[r * 256 + 192 + lane];
            #pragma unroll
            for (int o = 32; o >= 1; o >>= 1) sv += __shfl_xor(sv, o, 64);
            if (lane == 0) c1_g[b * 32 + h * 8 + r] = sv;
        }
        __syncthreads();
        #pragma unroll
        for (int qi = 0; qi < 8; ++qi) redc[qi * 256 + t] = 0.125f * a2[qi] * bv;
        __syncthreads();
        #pragma unroll
        for (int rep = 0; rep < 2; ++rep) {
            int r = w * 2 + rep;
            float sv = redc[r * 256 + lane] + redc[r * 256 + 64 + lane] +
                       redc[r * 256 + 128 + lane] + redc[r * 256 + 192 + lane];
            #pragma unroll
            for (int o = 32; o >= 1; o >>= 1) sv += __shfl_xor(sv, o, 64);
            if (lane == 0) c0_g[b * 32 + h * 8 + r] = sv;
        }
        __syncthreads();
    }
}

// ---------------------------------------------------------------------------
// Main fused pass. chunk = 32 tokens. lane = (tok = lane&31, s = lane>>5);
// lane owns 4 hq = wave*8 + s*4 + u. w' in LDS [granule][hq][4] (broadcast reads).
__global__ __launch_bounds__(256, 2) void k_attn(
    const float* __restrict__ inp, const float* __restrict__ wp_g,
    const float* __restrict__ c0_g, const float* __restrict__ c1_g,
    float* __restrict__ V_g, float* __restrict__ A0_g, float* __restrict__ A1_g,
    float* __restrict__ U_g, float* __restrict__ SM_g,
    float* __restrict__ out_vis, float* __restrict__ out_temp, int write_vis)
{
    extern __shared__ float sm[];
    float4* x4  = (float4*)sm;          // [32 tok][64 gran] = 8192 f (XOR swizzled)
    float* wl   = sm + 8192;            // [64 g][32 hq][4j] = 8192 f
    float* att  = sm + 16384;           // [32][36]: 32 a*rs | rs | rs*m
    float* redm = sm + 17536;           // [32][5]
    float* reds = sm + 17696;           // [32][5]

    const int t = threadIdx.x;
    const int lane = t & 63, wave = t >> 6;
    const int tok = lane & 31, s = lane >> 5;
    const int sw = tok & 7;
    const int b = blockIdx.y, kb = blockIdx.x;
    const int hqb = wave * 8 + s * 4;

    // load w' into LDS, reordered to [g][hq][4]
    {
        const float4* wp4 = (const float4*)(wp_g + (size_t)b * 8192);
        #pragma unroll
        for (int r = 0; r < 8; ++r) {
            int i4 = r * 256 + t;             // float4 index into [hq][64 g]
            int hq = i4 >> 6, g = i4 & 63;
            *(float4*)(wl + g * 128 + hq * 4) = wp4[i4];
        }
    }
    float c0r[4], c1r[4];
    #pragma unroll
    for (int u = 0; u < 4; ++u) {
        c0r[u] = c0_g[b * 32 + hqb + u];
        c1r[u] = c1_g[b * 32 + hqb + u];
    }

    float4 acc[8];
    #pragma unroll
    for (int u = 0; u < 8; ++u) acc[u] = make_float4(0.f, 0.f, 0.f, 0.f);
    float4 xsv = make_float4(0.f, 0.f, 0.f, 0.f);
    float csum[4] = {0.f, 0.f, 0.f, 0.f};
    float A1p[4]  = {0.f, 0.f, 0.f, 0.f};
    float SMp = 0.f;

    const float4* inp4 = (const float4*)inp + (size_t)b * NKV * 64;

    for (int ci = 0; ci < 8; ++ci) {
        const int n0 = (kb * 8 + ci) * 32;

        // ---- stage 32 raw tokens (granule-XOR swizzle) ----
        #pragma unroll
        for (int k2 = 0; k2 < 8; ++k2) {
            int gi = k2 * 256 + t;
            int tk = gi >> 6, g = gi & 63;
            x4[tk * 64 + (g ^ (tk & 7))] = inp4[(size_t)(n0 + tk) * 64 + g];
        }
        __syncthreads();    // A

        // ---- stats + dots in one pass ----
        float d0 = 0.f, d1 = 0.f, d2 = 0.f, d3 = 0.f, s0 = 0.f, s1 = 0.f;
        const float* wlb = wl + hqb * 4;
        #pragma unroll 4
        for (int g = 0; g < 64; ++g) {
            float4 xv = x4[tok * 64 + (g ^ sw)];
            s0 += xv.x + xv.y + xv.z + xv.w;
            s1 = fmaf(xv.x, xv.x, s1); s1 = fmaf(xv.y, xv.y, s1);
            s1 = fmaf(xv.z, xv.z, s1); s1 = fmaf(xv.w, xv.w, s1);
            const float* wp = wlb + g * 128;
            float4 w0 = *(const float4*)(wp);
            float4 w1 = *(const float4*)(wp + 4);
            float4 w2 = *(const float4*)(wp + 8);
            float4 w3 = *(const float4*)(wp + 12);
            d0 = fmaf(xv.x, w0.x, d0); d0 = fmaf(xv.y, w0.y, d0);
            d0 = fmaf(xv.z, w0.z, d0); d0 = fmaf(xv.w, w0.w, d0);
            d1 = fmaf(xv.x, w1.x, d1); d1 = fmaf(xv.y, w1.y, d1);
            d1 = fmaf(xv.z, w1.z, d1); d1 = fmaf(xv.w, w1.w, d1);
            d2 = fmaf(xv.x, w2.x, d2); d2 = fmaf(xv.y, w2.y, d2);
            d2 = fmaf(xv.z, w2.z, d2); d2 = fmaf(xv.w, w2.w, d2);
            d3 = fmaf(xv.x, w3.x, d3); d3 = fmaf(xv.y, w3.y, d3);
            d3 = fmaf(xv.z, w3.z, d3); d3 = fmaf(xv.w, w3.w, d3);
        }
        float m  = s0 * (1.f / 256.f);
        float rs = rsqrtf(s1 * (1.f / 256.f) - m * m + 1e-5f);
        float rm = rs * m;
        float lg0 = fmaf(rs, d0, fmaf(-rm, c1r[0], c0r[0]));
        float lg1 = fmaf(rs, d1, fmaf(-rm, c1r[1], c0r[1]));
        float lg2 = fmaf(rs, d2, fmaf(-rm, c1r[2], c0r[2]));
        float lg3 = fmaf(rs, d3, fmaf(-rm, c1r[3], c0r[3]));

        // ---- joint softmax over 32 (h,q) ----
        float pm = fmaxf(fmaxf(lg0, lg1), fmaxf(lg2, lg3));
        pm = fmaxf(pm, __shfl_xor(pm, 32, 64));
        if (lane < 32) redm[tok * 5 + wave] = pm;
        __syncthreads();    // B
        float mx = fmaxf(fmaxf(redm[tok * 5], redm[tok * 5 + 1]),
                         fmaxf(redm[tok * 5 + 2], redm[tok * 5 + 3]));
        float e0 = exp2f((lg0 - mx) * 1.44269504f);
        float e1 = exp2f((lg1 - mx) * 1.44269504f);
        float e2 = exp2f((lg2 - mx) * 1.44269504f);
        float e3 = exp2f((lg3 - mx) * 1.44269504f);
        float ps = e0 + e1 + e2 + e3;
        ps += __shfl_xor(ps, 32, 64);
        if (lane < 32) reds[tok * 5 + wave] = ps;
        __syncthreads();    // C
        float inv = 1.f / (reds[tok * 5] + reds[tok * 5 + 1] +
                           reds[tok * 5 + 2] + reds[tok * 5 + 3]);
        float a0v = e0 * inv, a1v = e1 * inv, a2v = e2 * inv, a3v = e3 * inv;
        csum[0] += a0v; csum[1] += a1v; csum[2] += a2v; csum[3] += a3v;
        A1p[0] = fmaf(a0v, rm, A1p[0]); A1p[1] = fmaf(a1v, rm, A1p[1]);
        A1p[2] = fmaf(a2v, rm, A1p[2]); A1p[3] = fmaf(a3v, rm, A1p[3]);
        float4 aw = make_float4(a0v * rs, a1v * rs, a2v * rs, a3v * rs);
        *(float4*)(att + tok * 36 + hqb) = aw;
        if (t < 32) { att[t * 36 + 32] = rs; att[t * 36 + 33] = rm; }
        __syncthreads();    // D

        // ---- attn_vis / attn_temp (last iter only) ----
        if (write_vis) {
            int tk = t >> 3, q = t & 7;
            float sv = att[tk * 36 + q] + att[tk * 36 + 8 + q] +
                       att[tk * 36 + 16 + q] + att[tk * 36 + 24 + q];
            float v = sv / att[tk * 36 + 32];
            size_t o = ((size_t)b * NKV + n0 + tk) * 8 + q;
            out_vis[o] = v; out_temp[o] = v;
        }

        // ---- y accumulation: V[hq][j] += (a*rs)[tok][hq] * x_raw[tok][j] ----
        {
            const int j = lane;
            #pragma unroll 2
            for (int tk = 0; tk < 32; ++tk) {
                float4 xv = x4[tk * 64 + (j ^ (tk & 7))];
                const float* ab = att + tk * 36 + wave * 8;
                float4 w0 = *(const float4*)(ab);
                float4 w1 = *(const float4*)(ab + 4);
                acc[0].x = fmaf(w0.x, xv.x, acc[0].x); acc[0].y = fmaf(w0.x, xv.y, acc[0].y);
                acc[0].z = fmaf(w0.x, xv.z, acc[0].z); acc[0].w = fmaf(w0.x, xv.w, acc[0].w);
                acc[1].x = fmaf(w0.y, xv.x, acc[1].x); acc[1].y = fmaf(w0.y, xv.y, acc[1].y);
                acc[1].z = fmaf(w0.y, xv.z, acc[1].z); acc[1].w = fmaf(w0.y, xv.w, acc[1].w);
                acc[2].x = fmaf(w0.z, xv.x, acc[2].x); acc[2].y = fmaf(w0.z, xv.y, acc[2].y);
                acc[2].z = fmaf(w0.z, xv.z, acc[2].z); acc[2].w = fmaf(w0.z, xv.w, acc[2].w);
                acc[3].x = fmaf(w0.w, xv.x, acc[3].x); acc[3].y = fmaf(w0.w, xv.y, acc[3].y);
                acc[3].z = fmaf(w0.w, xv.z, acc[3].z); acc[3].w = fmaf(w0.w, xv.w, acc[3].w);
                acc[4].x = fmaf(w1.x, xv.x, acc[4].x); acc[4].y = fmaf(w1.x, xv.y, acc[4].y);
                acc[4].z = fmaf(w1.x, xv.z, acc[4].z); acc[4].w = fmaf(w1.x, xv.w, acc[4].w);
                acc[5].x = fmaf(w1.y, xv.x, acc[5].x); acc[5].y = fmaf(w1.y, xv.y, acc[5].y);
                acc[5].z = fmaf(w1.y, xv.z, acc[5].z); acc[5].w = fmaf(w1.y, xv.w, acc[5].w);
                acc[6].x = fmaf(w1.z, xv.x, acc[6].x); acc[6].y = fmaf(w1.z, xv.y, acc[6].y);
                acc[6].z = fmaf(w1.z, xv.z, acc[6].z); acc[6].w = fmaf(w1.z, xv.w, acc[6].w);
                acc[7].x = fmaf(w1.w, xv.x, acc[7].x); acc[7].y = fmaf(w1.w, xv.y, acc[7].y);
                acc[7].z = fmaf(w1.w, xv.z, acc[7].z); acc[7].w = fmaf(w1.w, xv.w, acc[7].w);
                if (wave == 0) {
                    float rst = att[tk * 36 + 32];
                    xsv.x = fmaf(rst, xv.x, xsv.x); xsv.y = fmaf(rst, xv.y, xsv.y);
                    xsv.z = fmaf(rst, xv.z, xsv.z); xsv.w = fmaf(rst, xv.w, xsv.w);
                    SMp += att[tk * 36 + 33];
                }
            }
        }
        __syncthreads();    // E
    }

    // ---- final reductions ----
    #pragma unroll
    for (int o = 1; o <= 16; o <<= 1) {
        #pragma unroll
        for (int u = 0; u < 4; ++u) {
            csum[u] += __shfl_xor(csum[u], o, 64);
            A1p[u]  += __shfl_xor(A1p[u],  o, 64);
        }
    }
    if (tok == 0) {
        #pragma unroll
        for (int u = 0; u < 4; ++u) {
            atomicAdd(A0_g + b * 32 + hqb + u, csum[u]);
            atomicAdd(A1_g + b * 32 + hqb + u, A1p[u]);
        }
    }
    {
        const int j = lane;
        float* vb = V_g + ((size_t)b * 32 + wave * 8) * 256;
        #pragma unroll
        for (int u = 0; u < 8; ++u) {
            float* p = vb + u * 256 + j * 4;
            atomicAdd(p + 0, acc[u].x);
            atomicAdd(p + 1, acc[u].y);
            atomicAdd(p + 2, acc[u].z);
            atomicAdd(p + 3, acc[u].w);
        }
    }
    if (wave == 0) {
        float* p = U_g + b * 256 + lane * 4;
        atomicAdd(p + 0, xsv.x); atomicAdd(p + 1, xsv.y);
        atomicAdd(p + 2, xsv.z); atomicAdd(p + 3, xsv.w);
        if (lane == 0) atomicAdd(SM_g + b, SMp);
    }
}

// ---------------------------------------------------------------------------
// Fused per-slot-row: y-fold -> updates -> GRU -> LN -> MLP -> residual.
// grid 256: block = (b = blk>>3, qi = blk&7). bf16 weights for GRU/MLP.
__global__ __launch_bounds__(256) void k_slotrow(
    const float* __restrict__ V_g, const float* __restrict__ A0_g,
    const float* __restrict__ A1_g, const float* __restrict__ U_g,
    const float* __restrict__ SM_g,
    const float* __restrict__ g_in, const float* __restrict__ b_in,
    const float* __restrict__ Wv,
    const unsigned short* __restrict__ wih_bf, const unsigned short* __restrict__ whh_bf,
    const float* __restrict__ bih, const float* __restrict__ bhh,
    const float* __restrict__ gm, const float* __restrict__ bm,
    const unsigned short* __restrict__ w1_bf, const float* __restrict__ b1,
    const unsigned short* __restrict__ w2_bf, const float* __restrict__ b2,
    float* __restrict__ slot, float* __restrict__ out_slots)
{
    __shared__ float ly[4 * 256];
    __shared__ float lup[256];
    __shared__ float lsp[256];
    __shared__ float lmm[256];
    __shared__ float lh1[1024];
    __shared__ float lred[8];
    const int t = threadIdx.x;
    const int b = blockIdx.x >> 3, qi = blockIdx.x & 7;
    const int lane = t & 63, w = t >> 6;

    const float gj = g_in[t], bj = b_in[t];
    const float U_t = U_g[b * 256 + t];
    const float SM_b = SM_g[b];
    #pragma unroll
    for (int h = 0; h < 4; ++h) {
        int hq = h * 8 + qi;
        float A0 = A0_g[b * 32 + hq], A1 = A1_g[b * 32 + hq];
        float den = A0 + EPSR * (float)NKV;
        float vv = V_g[((size_t)b * 32 + hq) * 256 + t];
        float num = gj * (vv - A1) + bj * A0 +
                    EPSR * (gj * U_t - gj * SM_b + (float)NKV * bj);
        ly[h * 256 + t] = num / den;
    }
    float spv = slot[((size_t)b * 8 + qi) * 256 + t];
    lsp[t] = spv;
    __syncthreads();

    // updates row: up[t] = sum_j y[h=t>>6][j] * Wv[t][j]
    {
        const int h = t >> 6;
        float acc = 0.f;
        const float4* wv4 = (const float4*)Wv;
        const float4* y4 = (const float4*)(ly + h * 256);
        for (int j4 = 0; j4 < 64; ++j4) {
            float4 wv = wv4[(size_t)t * 64 + j4];
            float4 yv = y4[j4];
            acc = fmaf(wv.x, yv.x, acc); acc = fmaf(wv.y, yv.y, acc);
            acc = fmaf(wv.z, yv.z, acc); acc = fmaf(wv.w, yv.w, acc);
        }
        lup[t] = acc;
    }
    __syncthreads();

    // GRU gates at col t
    float gx0 = 0.f, gx1 = 0.f, gx2 = 0.f, gh0 = 0.f, gh1 = 0.f, gh2 = 0.f;
    {
        const uint4* wih4 = (const uint4*)wih_bf;
        const uint4* whh4 = (const uint4*)whh_bf;
        const float4* up4 = (const float4*)lup;
        const float4* sp4 = (const float4*)lsp;
        const size_t r0 = (size_t)t * 32, r1 = (size_t)(256 + t) * 32, r2 = (size_t)(512 + t) * 32;
        for (int jj = 0; jj < 32; ++jj) {
            float4 ua = up4[jj * 2], ub = up4[jj * 2 + 1];
            float4 sa = sp4[jj * 2], sb = sp4[jj * 2 + 1];
            gx0 += dot8(wih4[r0 + jj], ua, ub);
            gx1 += dot8(wih4[r1 + jj], ua, ub);
            gx2 += dot8(wih4[r2 + jj], ua, ub);
            gh0 += dot8(whh4[r0 + jj], sa, sb);
            gh1 += dot8(whh4[r1 + jj], sa, sb);
            gh2 += dot8(whh4[r2 + jj], sa, sb);
        }
    }
    float rr = 1.f / (1.f + __expf(-(gx0 + bih[t] + gh0 + bhh[t])));
    float zz = 1.f / (1.f + __expf(-(gx1 + bih[256 + t] + gh1 + bhh[256 + t])));
    float nn = tanhf(gx2 + bih[512 + t] + rr * (gh2 + bhh[512 + t]));
    float smid = (1.f - zz) * nn + zz * spv;
    __syncthreads();
    lsp[t] = smid;

    // LN over 256 cols
    {
        float s0 = smid, s1 = smid * smid;
        #pragma unroll
        for (int o = 32; o >= 1; o >>= 1) { s0 += __shfl_xor(s0, o, 64); s1 += __shfl_xor(s1, o, 64); }
        if (lane == 0) { lred[w] = s0; lred[4 + w] = s1; }
    }
    __syncthreads();
    {
        float mu = (lred[0] + lred[1] + lred[2] + lred[3]) * (1.f / 256.f);
        float q2 = (lred[4] + lred[5] + lred[6] + lred[7]) * (1.f / 256.f);
        float rsg = rsqrtf(q2 - mu * mu + 1e-5f);
        lmm[t] = (smid - mu) * rsg * gm[t] + bm[t];
    }
    __syncthreads();

    // MLP layer 1: h1[g*256+t]
    {
        const uint4* w14 = (const uint4*)w1_bf;
        const float4* mm4 = (const float4*)lmm;
        float h[4] = {0.f, 0.f, 0.f, 0.f};
        for (int jj = 0; jj < 32; ++jj) {
            float4 ma = mm4[jj * 2], mb = mm4[jj * 2 + 1];
            #pragma unroll
            for (int g = 0; g < 4; ++g)
                h[g] += dot8(w14[(size_t)(g * 256 + t) * 32 + jj], ma, mb);
        }
        #pragma unroll
        for (int g = 0; g < 4; ++g)
            lh1[g * 256 + t] = fmaxf(h[g] + b1[g * 256 + t], 0.f);
    }
    __syncthreads();

    // MLP layer 2 + residual
    {
        const uint4* w24 = (const uint4*)w2_bf + (size_t)t * 128;
        const float4* h14 = (const float4*)lh1;
        float acc = 0.f;
        for (int kk = 0; kk < 128; ++kk)
            acc += dot8(w24[kk], h14[kk * 2], h14[kk * 2 + 1]);
        float res = smid + acc + b2[t];
        size_t o = ((size_t)b * 8 + qi) * 256 + t;
        slot[o] = res;
        if (out_slots) out_slots[o] = res;
    }
}

// ---------------------------------------------------------------------------
extern "C" void kernel_launch(void* const* d_in, const int* in_sizes, int n_in,
                              void* d_out, int out_size, void* d_ws, size_t ws_size,
                              hipStream_t stream) {
    const float* inp     = (const float*)d_in[0];
    const float* slots0  = (const float*)d_in[1];
    const float* ln_in_g = (const float*)d_in[2];
    const float* ln_in_b = (const float*)d_in[3];
    const float* ln_s_g  = (const float*)d_in[4];
    const float* ln_s_b  = (const float*)d_in[5];
    const float* ln_m_g  = (const float*)d_in[6];
    const float* ln_m_b  = (const float*)d_in[7];
    const float* Wq  = (const float*)d_in[8];
    const float* Wk  = (const float*)d_in[9];
    const float* Wv  = (const float*)d_in[10];
    const float* Wih = (const float*)d_in[11];
    const float* Whh = (const float*)d_in[12];
    const float* bih = (const float*)d_in[13];
    const float* bhh = (const float*)d_in[14];
    const float* W1  = (const float*)d_in[15];
    const float* b1  = (const float*)d_in[16];
    const float* W2  = (const float*)d_in[17];
    const float* b2  = (const float*)d_in[18];

    float* ws = (float*)d_ws;
    float* V_g  = ws + WS_V;
    float* wp_g = ws + WS_WP;
    float* A0_g = ws + WS_A0;
    float* A1_g = ws + WS_A1;
    float* U_g  = ws + WS_U;
    float* SM_g = ws + WS_SM;
    float* c0_g = ws + WS_C0;
    float* c1_g = ws + WS_C1;
    float* slot = ws + WS_SLOT;
    unsigned short* bfbase = (unsigned short*)((char*)d_ws + WS_BF_BYTES);
    unsigned short* wih_bf = bfbase + BF_WIH;
    unsigned short* whh_bf = bfbase + BF_WHH;
    unsigned short* w1_bf  = bfbase + BF_W1;
    unsigned short* w2_bf  = bfbase + BF_W2;

    float* out_slots = (float*)d_out;
    float* out_vis   = out_slots + 32 * 8 * 256;
    float* out_temp  = out_vis + 32 * 4096 * 8;

    (void)hipFuncSetAttribute((const void*)k_attn,
                              hipFuncAttributeMaxDynamicSharedMemorySize, SMEM_ATTN);

    k_cvt<<<768, 256, 0, stream>>>(Wih, wih_bf, 196608);
    k_cvt<<<768, 256, 0, stream>>>(Whh, whh_bf, 196608);
    k_cvt<<<1024, 256, 0, stream>>>(W1, w1_bf, 262144);
    k_cvt<<<1024, 256, 0, stream>>>(W2, w2_bf, 262144);
    k_copy<<<256, 256, 0, stream>>>(slots0, slot, 65536);

    for (int it = 0; it < 3; ++it) {
        k_slotprep<<<32, 256, 0, stream>>>(slot, ln_s_g, ln_s_b, Wq, Wk,
                                           ln_in_g, ln_in_b, wp_g, c0_g, c1_g,
                                           V_g, A0_g, A1_g, U_g, SM_g);
        k_attn<<<dim3(16, 32), 256, SMEM_ATTN, stream>>>(
            inp, wp_g, c0_g, c1_g, V_g, A0_g, A1_g, U_g, SM_g,
            out_vis, out_temp, (it == 2) ? 1 : 0);
        k_slotrow<<<256, 256, 0, stream>>>(
            V_g, A0_g, A1_g, U_g, SM_g, ln_in_g, ln_in_b, Wv,
            wih_bf, whh_bf, bih, bhh, ln_m_g, ln_m_b, w1_bf, b1, w2_bf, b2,
            slot, (it == 2) ? out_slots : nullptr);
    }
}

// Round 3
// 612.969 us; speedup vs baseline: 1.8996x; 1.6160x over previous
//
#include <hip/hip_runtime.h>
#include <math.h>

// ---------------------------------------------------------------------------
// SlotAttention fused forward. MFMA (bf16) attention path, bf16 GRU/MLP weights.
//   logit(log2-units) = dot(xs, w'') - rm*c1 + c0,  xs = rs*x_raw (bf16)
//   w'' = 0.125*log2e * g_in (.) (q@Wk),  c1 = sum g*wkq'', c0 = sum b*wkq''
//   y-fold: updates_pre[hq,j] = (g_j*(V - A1) + b_j*A0)/(A0 + eps*N)
//     V = sum_t a*rs*x,  A1 = sum_t a*rm,  A0 = sum_t a   (eps-numerator ~1e-8 rel, dropped)
// ---------------------------------------------------------------------------

#define NKV   4096
#define DD    256
#define HQN   32
#define EPSR  1e-8f

// workspace layout (float offsets)
#define WS_V     0                      // 262144
#define WS_A0    262144                 // 1024
#define WS_A1    263168                 // 1024
#define WS_C0    264192                 // 1024
#define WS_C1    265216                 // 1024
#define WS_SLOT  266240                 // 65536
#define WS_WPBF  331776                 // 262144 ushort = 131072 floats
#define WS_BF_BYTES (462848 * 4)        // bf16 GRU/MLP weights
#define BF_WIH   0
#define BF_WHH   196608
#define BF_W1    393216
#define BF_W2    655360

typedef float f32x4 __attribute__((ext_vector_type(4)));
typedef short s16x8 __attribute__((ext_vector_type(8)));
typedef int   v2i   __attribute__((ext_vector_type(2)));

__device__ __forceinline__ unsigned bfr(float f) {
    unsigned u = __float_as_uint(f);
    return (u + 0x7fffu + ((u >> 16) & 1u)) >> 16;
}
__device__ __forceinline__ unsigned pk2(float lo, float hi) {
    return bfr(lo) | (bfr(hi) << 16);
}
__device__ __forceinline__ float bf2f(unsigned short us) {
    return __uint_as_float((unsigned)us << 16);
}
__device__ __forceinline__ float bflo(unsigned u) { return __uint_as_float(u << 16); }
__device__ __forceinline__ float bfhi(unsigned u) { return __uint_as_float(u & 0xffff0000u); }

__device__ __forceinline__ float dot8(uint4 w, float4 a, float4 b) {
    float s = 0.f;
    s = fmaf(bflo(w.x), a.x, s); s = fmaf(bfhi(w.x), a.y, s);
    s = fmaf(bflo(w.y), a.z, s); s = fmaf(bfhi(w.y), a.w, s);
    s = fmaf(bflo(w.z), b.x, s); s = fmaf(bfhi(w.z), b.y, s);
    s = fmaf(bflo(w.w), b.z, s); s = fmaf(bfhi(w.w), b.w, s);
    return s;
}

__device__ __forceinline__ v2i tr_read(unsigned addr) {
    v2i d;
    asm volatile("ds_read_b64_tr_b16 %0, %1" : "=v"(d) : "v"(addr));
    return d;
}
__device__ __forceinline__ s16x8 mk_frag(v2i a, v2i b) {
    union { int i[4]; s16x8 s; } u;
    u.i[0] = a.x; u.i[1] = a.y; u.i[2] = b.x; u.i[3] = b.y;
    return u.s;
}

__global__ __launch_bounds__(256) void k_cvt(const float* __restrict__ in,
                                             unsigned short* __restrict__ out, int n) {
    int i = blockIdx.x * 256 + threadIdx.x;
    if (i < n) out[i] = (unsigned short)bfr(in[i]);
}

__global__ __launch_bounds__(256) void k_copy(const float* __restrict__ in,
                                              float* __restrict__ out, int n) {
    int i = blockIdx.x * 256 + threadIdx.x;
    if (i < n) out[i] = in[i];
}

// ---------------------------------------------------------------------------
// Per-iteration slot prep (one block per batch).
__global__ __launch_bounds__(256) void k_slotprep(
    const float* __restrict__ slots, const float* __restrict__ g_s, const float* __restrict__ b_s,
    const float* __restrict__ Wq, const float* __restrict__ Wk,
    const float* __restrict__ g_in, const float* __restrict__ b_in,
    unsigned short* __restrict__ wp_bf, float* __restrict__ c0_g, float* __restrict__ c1_g,
    float* __restrict__ V_g, float* __restrict__ A0_g, float* __restrict__ A1_g)
{
    __shared__ float s_lds[2048];
    __shared__ float qf[2048];
    __shared__ float redc[2048];
    const int t = threadIdx.x;
    const int b = blockIdx.x;
    const int lane = t & 63, w = t >> 6;
    const float LNS = 0.125f * 1.44269504f;

    #pragma unroll
    for (int k = 0; k < 32; ++k) V_g[(size_t)b * 8192 + k * 256 + t] = 0.f;
    if (t < 32) { A0_g[b * 32 + t] = 0.f; A1_g[b * 32 + t] = 0.f; }

    // LN(slots)
    for (int r = w; r < 8; r += 4) {
        const float4 v = ((const float4*)(slots + ((size_t)b * 8 + r) * 256))[lane];
        float s0 = v.x + v.y + v.z + v.w;
        float s1 = v.x * v.x + v.y * v.y + v.z * v.z + v.w * v.w;
        #pragma unroll
        for (int o = 32; o >= 1; o >>= 1) { s0 += __shfl_xor(s0, o, 64); s1 += __shfl_xor(s1, o, 64); }
        float m = s0 * (1.f / 256.f);
        float rs = rsqrtf(s1 * (1.f / 256.f) - m * m + 1e-5f);
        float4 gg = ((const float4*)g_s)[lane];
        float4 bb = ((const float4*)b_s)[lane];
        float4 nn;
        nn.x = (v.x - m) * rs * gg.x + bb.x;
        nn.y = (v.y - m) * rs * gg.y + bb.y;
        nn.z = (v.z - m) * rs * gg.z + bb.z;
        nn.w = (v.w - m) * rs * gg.w + bb.w;
        ((float4*)(s_lds + r * 256))[lane] = nn;
    }
    __syncthreads();

    // qf[qi][e=t] = sum_j s[qi][j] * Wq[t][j]
    {
        float a[8];
        #pragma unroll
        for (int qi = 0; qi < 8; ++qi) a[qi] = 0.f;
        const float4* wq4 = (const float4*)Wq;
        for (int j4 = 0; j4 < 64; ++j4) {
            float4 wv = wq4[(size_t)t * 64 + j4];
            #pragma unroll
            for (int qi = 0; qi < 8; ++qi) {
                float4 sv = *(const float4*)(s_lds + qi * 256 + j4 * 4);
                a[qi] = fmaf(sv.x, wv.x, a[qi]);
                a[qi] = fmaf(sv.y, wv.y, a[qi]);
                a[qi] = fmaf(sv.z, wv.z, a[qi]);
                a[qi] = fmaf(sv.w, wv.w, a[qi]);
            }
        }
        #pragma unroll
        for (int qi = 0; qi < 8; ++qi) qf[qi * 256 + t] = a[qi];
    }
    __syncthreads();

    const float gv = g_in[t], bv = b_in[t];
    for (int h = 0; h < 4; ++h) {
        float a2[8];
        #pragma unroll
        for (int qi = 0; qi < 8; ++qi) a2[qi] = 0.f;
        for (int d = 0; d < 64; ++d) {
            float wv = Wk[(size_t)(h * 64 + d) * 256 + t];
            #pragma unroll
            for (int qi = 0; qi < 8; ++qi) a2[qi] = fmaf(qf[qi * 256 + h * 64 + d], wv, a2[qi]);
        }
        #pragma unroll
        for (int qi = 0; qi < 8; ++qi) {
            float kv = LNS * a2[qi];
            float we = kv * gv;
            wp_bf[((size_t)b * HQN + h * 8 + qi) * 256 + t] = (unsigned short)bfr(we);
            redc[qi * 256 + t] = we;
        }
        __syncthreads();
        #pragma unroll
        for (int rep = 0; rep < 2; ++rep) {
            int r = w * 2 + rep;
            float sv = redc[r * 256 + lane] + redc[r * 256 + 64 + lane] +
                       redc[r * 256 + 128 + lane] + redc[r * 256 + 192 + lane];
            #pragma unroll
            for (int o = 32; o >= 1; o >>= 1) sv += __shfl_xor(sv, o, 64);
            if (lane == 0) c1_g[b * 32 + h * 8 + r] = sv;
        }
        __syncthreads();
        #pragma unroll
        for (int qi = 0; qi < 8; ++qi) redc[qi * 256 + t] = LNS * a2[qi] * bv;
        __syncthreads();
        #pragma unroll
        for (int rep = 0; rep < 2; ++rep) {
            int r = w * 2 + rep;
            float sv = redc[r * 256 + lane] + redc[r * 256 + 64 + lane] +
                       redc[r * 256 + 128 + lane] + redc[r * 256 + 192 + lane];
            #pragma unroll
            for (int o = 32; o >= 1; o >>= 1) sv += __shfl_xor(sv, o, 64);
            if (lane == 0) c0_g[b * 32 + h * 8 + r] = sv;
        }
        __syncthreads();
    }
}

// ---------------------------------------------------------------------------
// Main fused MFMA pass. 1024 blocks (32 kb x 32 b), 4 chunks of 32 tokens each.
__global__ __launch_bounds__(256, 4) void k_attn(
    const float* __restrict__ inp, const unsigned short* __restrict__ wp_bf,
    const float* __restrict__ c0_g, const float* __restrict__ c1_g,
    float* __restrict__ V_g, float* __restrict__ A0_g, float* __restrict__ A1_g,
    float* __restrict__ out_vis, float* __restrict__ out_temp, int write_vis)
{
    // xs tiles: 16 subtiles [32 tok][16 j] bf16, stride 1040B (conflict-free writes)
    __shared__ unsigned short xb[16 * 520];     // 16640 B
    __shared__ unsigned short wl[8192];         // 16384 B, [hq][k] swizzled
    __shared__ unsigned short pt[1024];         // 2048 B,  [hq][tok] swizzled
    __shared__ float stats[32];                 // rm per token
    __shared__ float redm[64];
    __shared__ float reds[64];

    const int t = threadIdx.x;
    const int l = t & 63, w = t >> 6;
    const int g = l >> 4, li = l & 15;
    const int b = blockIdx.y, kb = blockIdx.x;

    char* xbB = (char*)xb;
    char* wlB = (char*)wl;
    char* ptB = (char*)pt;

    const int tok_s = t >> 3, seg8 = t & 7;

    // stage W'' into LDS (swizzled rows [hq][k], slot ^= hq&7)
    {
        const uint4* wp4 = (const uint4*)wp_bf + ((size_t)b * 8192 + (t >> 3) * 256 + (t & 7) * 32) / 8;
        const int hq = t >> 3, sg = t & 7;
        #pragma unroll
        for (int q = 0; q < 4; ++q) {
            uint4 v = wp4[q];
            *(uint4*)(wlB + hq * 512 + (((sg * 4 + q) ^ (hq & 7)) * 16)) = v;
        }
    }

    const int Mt = w & 1, Nt = w >> 1;          // S-phase tile (tok-half, hq-half)
    const int hqB = Nt * 16 + li;
    const float c0r = c0_g[b * 32 + hqB];
    const float c1r = c1_g[b * 32 + hqB];
    const int MtV = w >> 1, ntb = (w & 1) * 8;  // V-phase tile (hq-half, j-set)
    const int hqA = MtV * 16 + li;

    f32x4 av[8];
    #pragma unroll
    for (int u = 0; u < 8; ++u) av[u] = (f32x4){0.f, 0.f, 0.f, 0.f};
    float A0acc = 0.f, A1acc = 0.f;

    const unsigned xbase = (unsigned)(uintptr_t)xbB;

    for (int ci = 0; ci < 4; ++ci) {
        const int n0 = (kb * 4 + ci) * 32;

        // ---- load 32 raw floats per thread, stats, scale, pack to xs tiles ----
        const float4* row4 = (const float4*)(inp + ((size_t)b * NKV + n0 + tok_s) * 256);
        float4 ld[8];
        #pragma unroll
        for (int c = 0; c < 2; ++c)
            #pragma unroll
            for (int q = 0; q < 4; ++q)
                ld[c * 4 + q] = row4[c * 32 + seg8 * 4 + q];
        float s0 = 0.f, s1 = 0.f;
        #pragma unroll
        for (int u = 0; u < 8; ++u) {
            float4 v = ld[u];
            s0 += v.x + v.y + v.z + v.w;
            s1 = fmaf(v.x, v.x, s1); s1 = fmaf(v.y, v.y, s1);
            s1 = fmaf(v.z, v.z, s1); s1 = fmaf(v.w, v.w, s1);
        }
        s0 += __shfl_xor(s0, 1, 64); s1 += __shfl_xor(s1, 1, 64);
        s0 += __shfl_xor(s0, 2, 64); s1 += __shfl_xor(s1, 2, 64);
        s0 += __shfl_xor(s0, 4, 64); s1 += __shfl_xor(s1, 4, 64);
        float m  = s0 * (1.f / 256.f);
        float rs = rsqrtf(s1 * (1.f / 256.f) - m * m + 1e-5f);
        if (seg8 == 0) stats[tok_s] = rs * m;
        #pragma unroll
        for (int c = 0; c < 2; ++c) {
            int nt = seg8 + 8 * c;
            #pragma unroll
            for (int h = 0; h < 2; ++h) {
                float4 fa = ld[c * 4 + h * 2], fb = ld[c * 4 + h * 2 + 1];
                uint4 pk;
                pk.x = pk2(rs * fa.x, rs * fa.y); pk.y = pk2(rs * fa.z, rs * fa.w);
                pk.z = pk2(rs * fb.x, rs * fb.y); pk.w = pk2(rs * fb.z, rs * fb.w);
                *(uint4*)(xbB + nt * 1040 + tok_s * 32 + h * 16) = pk;
            }
        }
        __syncthreads();   // A: xs + stats ready

        // ---- S = Xs * W''^T  (16x16 tile per wave, K=256) ----
        f32x4 accS = (f32x4){0.f, 0.f, 0.f, 0.f};
        #pragma unroll
        for (int kk = 0; kk < 8; ++kk) {
            s16x8 af = *(const s16x8*)(xbB + (kk * 2 + (g >> 1)) * 1040 +
                                       (Mt * 16 + li) * 32 + (g & 1) * 16);
            s16x8 bf = *(const s16x8*)(wlB + hqB * 512 + (((kk * 4 + g) ^ (hqB & 7)) * 16));
            accS = __builtin_amdgcn_mfma_f32_16x16x32_bf16(af, bf, accS, 0, 0, 0);
        }

        // ---- logits + joint softmax over 32 hq ----
        float lg[4], rmv[4], ex[4], aa[4];
        #pragma unroll
        for (int r = 0; r < 4; ++r) {
            rmv[r] = stats[Mt * 16 + g * 4 + r];
            lg[r] = accS[r] - rmv[r] * c1r + c0r;
        }
        #pragma unroll
        for (int r = 0; r < 4; ++r) {
            float v = lg[r];
            v = fmaxf(v, __shfl_xor(v, 1, 64));
            v = fmaxf(v, __shfl_xor(v, 2, 64));
            v = fmaxf(v, __shfl_xor(v, 4, 64));
            v = fmaxf(v, __shfl_xor(v, 8, 64));
            if (li == 0) redm[(Mt * 16 + g * 4 + r) * 2 + Nt] = v;
        }
        __syncthreads();   // B
        #pragma unroll
        for (int r = 0; r < 4; ++r) {
            int tokr = Mt * 16 + g * 4 + r;
            float mx = fmaxf(redm[tokr * 2], redm[tokr * 2 + 1]);
            ex[r] = exp2f(lg[r] - mx);
            float v = ex[r];
            v += __shfl_xor(v, 1, 64);
            v += __shfl_xor(v, 2, 64);
            v += __shfl_xor(v, 4, 64);
            v += __shfl_xor(v, 8, 64);
            if (li == 0) reds[tokr * 2 + Nt] = v;
        }
        __syncthreads();   // C
        #pragma unroll
        for (int r = 0; r < 4; ++r) {
            int tokr = Mt * 16 + g * 4 + r;
            float tot = reds[tokr * 2] + reds[tokr * 2 + 1];
            aa[r] = ex[r] / tot;
            A0acc += aa[r];
            A1acc = fmaf(aa[r], rmv[r], A1acc);
        }
        {
            uint2 pw;
            pw.x = pk2(aa[0], aa[1]);
            pw.y = pk2(aa[2], aa[3]);
            int tokb = Mt * 16 + g * 4;
            int slot = (tokb >> 3) ^ ((hqB >> 1) & 3);
            *(uint2*)(ptB + hqB * 64 + slot * 16 + (tokb & 7) * 2) = pw;
        }
        __syncthreads();   // D: P ready

        if (write_vis) {
            int tk = t >> 3, q = t & 7;
            float sv = 0.f;
            #pragma unroll
            for (int h = 0; h < 4; ++h) {
                int hq = h * 8 + q;
                int slot = (tk >> 3) ^ ((hq >> 1) & 3);
                sv += bf2f(*(const unsigned short*)(ptB + hq * 64 + slot * 16 + (tk & 7) * 2));
            }
            size_t o = ((size_t)b * NKV + n0 + tk) * 8 + q;
            out_vis[o] = sv; out_temp[o] = sv;
        }

        // ---- V += P^T(A) * Xs(B)  via tr-reads ----
        {
            s16x8 pa = *(const s16x8*)(ptB + hqA * 64 + ((g ^ ((hqA >> 1) & 3)) * 16));
            unsigned abase = xbase + g * 256 + li * 8;
            v2i t0a = tr_read(abase + (ntb + 0) * 1040);
            v2i t0b = tr_read(abase + (ntb + 0) * 1040 + 128);
            v2i t1a = tr_read(abase + (ntb + 1) * 1040);
            v2i t1b = tr_read(abase + (ntb + 1) * 1040 + 128);
            v2i t2a = tr_read(abase + (ntb + 2) * 1040);
            v2i t2b = tr_read(abase + (ntb + 2) * 1040 + 128);
            v2i t3a = tr_read(abase + (ntb + 3) * 1040);
            v2i t3b = tr_read(abase + (ntb + 3) * 1040 + 128);
            asm volatile("s_waitcnt lgkmcnt(0)" ::: "memory");
            __builtin_amdgcn_sched_barrier(0);
            av[0] = __builtin_amdgcn_mfma_f32_16x16x32_bf16(pa, mk_frag(t0a, t0b), av[0], 0, 0, 0);
            av[1] = __builtin_amdgcn_mfma_f32_16x16x32_bf16(pa, mk_frag(t1a, t1b), av[1], 0, 0, 0);
            av[2] = __builtin_amdgcn_mfma_f32_16x16x32_bf16(pa, mk_frag(t2a, t2b), av[2], 0, 0, 0);
            av[3] = __builtin_amdgcn_mfma_f32_16x16x32_bf16(pa, mk_frag(t3a, t3b), av[3], 0, 0, 0);
            v2i t4a = tr_read(abase + (ntb + 4) * 1040);
            v2i t4b = tr_read(abase + (ntb + 4) * 1040 + 128);
            v2i t5a = tr_read(abase + (ntb + 5) * 1040);
            v2i t5b = tr_read(abase + (ntb + 5) * 1040 + 128);
            v2i t6a = tr_read(abase + (ntb + 6) * 1040);
            v2i t6b = tr_read(abase + (ntb + 6) * 1040 + 128);
            v2i t7a = tr_read(abase + (ntb + 7) * 1040);
            v2i t7b = tr_read(abase + (ntb + 7) * 1040 + 128);
            asm volatile("s_waitcnt lgkmcnt(0)" ::: "memory");
            __builtin_amdgcn_sched_barrier(0);
            av[4] = __builtin_amdgcn_mfma_f32_16x16x32_bf16(pa, mk_frag(t4a, t4b), av[4], 0, 0, 0);
            av[5] = __builtin_amdgcn_mfma_f32_16x16x32_bf16(pa, mk_frag(t5a, t5b), av[5], 0, 0, 0);
            av[6] = __builtin_amdgcn_mfma_f32_16x16x32_bf16(pa, mk_frag(t6a, t6b), av[6], 0, 0, 0);
            av[7] = __builtin_amdgcn_mfma_f32_16x16x32_bf16(pa, mk_frag(t7a, t7b), av[7], 0, 0, 0);
        }
        __syncthreads();   // E: xb/pt free for next chunk
    }

    // ---- final global accumulation ----
    A0acc += __shfl_xor(A0acc, 16, 64); A0acc += __shfl_xor(A0acc, 32, 64);
    A1acc += __shfl_xor(A1acc, 16, 64); A1acc += __shfl_xor(A1acc, 32, 64);
    if (g == 0) {
        atomicAdd(A0_g + b * 32 + hqB, A0acc);
        atomicAdd(A1_g + b * 32 + hqB, A1acc);
    }
    #pragma unroll
    for (int i = 0; i < 8; ++i) {
        int j = (ntb + i) * 16 + li;
        #pragma unroll
        for (int r = 0; r < 4; ++r) {
            int hq = MtV * 16 + g * 4 + r;
            atomicAdd(V_g + ((size_t)b * 32 + hq) * 256 + j, av[i][r]);
        }
    }
}

// ---------------------------------------------------------------------------
// Fused per-slot-row: y-fold -> updates -> GRU -> LN -> MLP -> residual.
__global__ __launch_bounds__(256) void k_slotrow(
    const float* __restrict__ V_g, const float* __restrict__ A0_g,
    const float* __restrict__ A1_g,
    const float* __restrict__ g_in, const float* __restrict__ b_in,
    const float* __restrict__ Wv,
    const unsigned short* __restrict__ wih_bf, const unsigned short* __restrict__ whh_bf,
    const float* __restrict__ bih, const float* __restrict__ bhh,
    const float* __restrict__ gm, const float* __restrict__ bm,
    const unsigned short* __restrict__ w1_bf, const float* __restrict__ b1,
    const unsigned short* __restrict__ w2_bf, const float* __restrict__ b2,
    float* __restrict__ slot, float* __restrict__ out_slots)
{
    __shared__ float ly[4 * 256];
    __shared__ float lup[256];
    __shared__ float lsp[256];
    __shared__ float lmm[256];
    __shared__ float lh1[1024];
    __shared__ float lred[8];
    const int t = threadIdx.x;
    const int b = blockIdx.x >> 3, qi = blockIdx.x & 7;
    const int lane = t & 63, w = t >> 6;

    const float gj = g_in[t], bj = b_in[t];
    #pragma unroll
    for (int h = 0; h < 4; ++h) {
        int hq = h * 8 + qi;
        float A0 = A0_g[b * 32 + hq], A1 = A1_g[b * 32 + hq];
        float den = A0 + EPSR * (float)NKV;
        float vv = V_g[((size_t)b * 32 + hq) * 256 + t];
        ly[h * 256 + t] = (gj * (vv - A1) + bj * A0) / den;
    }
    float spv = slot[((size_t)b * 8 + qi) * 256 + t];
    lsp[t] = spv;
    __syncthreads();

    {
        const int h = t >> 6;
        float acc = 0.f;
        const float4* wv4 = (const float4*)Wv;
        const float4* y4 = (const float4*)(ly + h * 256);
        for (int j4 = 0; j4 < 64; ++j4) {
            float4 wv = wv4[(size_t)t * 64 + j4];
            float4 yv = y4[j4];
            acc = fmaf(wv.x, yv.x, acc); acc = fmaf(wv.y, yv.y, acc);
            acc = fmaf(wv.z, yv.z, acc); acc = fmaf(wv.w, yv.w, acc);
        }
        lup[t] = acc;
    }
    __syncthreads();

    float gx0 = 0.f, gx1 = 0.f, gx2 = 0.f, gh0 = 0.f, gh1 = 0.f, gh2 = 0.f;
    {
        const uint4* wih4 = (const uint4*)wih_bf;
        const uint4* whh4 = (const uint4*)whh_bf;
        const float4* up4 = (const float4*)lup;
        const float4* sp4 = (const float4*)lsp;
        const size_t r0 = (size_t)t * 32, r1 = (size_t)(256 + t) * 32, r2 = (size_t)(512 + t) * 32;
        for (int jj = 0; jj < 32; ++jj) {
            float4 ua = up4[jj * 2], ub = up4[jj * 2 + 1];
            float4 sa = sp4[jj * 2], sb = sp4[jj * 2 + 1];
            gx0 += dot8(wih4[r0 + jj], ua, ub);
            gx1 += dot8(wih4[r1 + jj], ua, ub);
            gx2 += dot8(wih4[r2 + jj], ua, ub);
            gh0 += dot8(whh4[r0 + jj], sa, sb);
            gh1 += dot8(whh4[r1 + jj], sa, sb);
            gh2 += dot8(whh4[r2 + jj], sa, sb);
        }
    }
    float rr = 1.f / (1.f + __expf(-(gx0 + bih[t] + gh0 + bhh[t])));
    float zz = 1.f / (1.f + __expf(-(gx1 + bih[256 + t] + gh1 + bhh[256 + t])));
    float nn = tanhf(gx2 + bih[512 + t] + rr * (gh2 + bhh[512 + t]));
    float smid = (1.f - zz) * nn + zz * spv;
    __syncthreads();
    lsp[t] = smid;

    {
        float s0 = smid, s1 = smid * smid;
        #pragma unroll
        for (int o = 32; o >= 1; o >>= 1) { s0 += __shfl_xor(s0, o, 64); s1 += __shfl_xor(s1, o, 64); }
        if (lane == 0) { lred[w] = s0; lred[4 + w] = s1; }
    }
    __syncthreads();
    {
        float mu = (lred[0] + lred[1] + lred[2] + lred[3]) * (1.f / 256.f);
        float q2 = (lred[4] + lred[5] + lred[6] + lred[7]) * (1.f / 256.f);
        float rsg = rsqrtf(q2 - mu * mu + 1e-5f);
        lmm[t] = (smid - mu) * rsg * gm[t] + bm[t];
    }
    __syncthreads();

    {
        const uint4* w14 = (const uint4*)w1_bf;
        const float4* mm4 = (const float4*)lmm;
        float h[4] = {0.f, 0.f, 0.f, 0.f};
        for (int jj = 0; jj < 32; ++jj) {
            float4 ma = mm4[jj * 2], mb = mm4[jj * 2 + 1];
            #pragma unroll
            for (int gq = 0; gq < 4; ++gq)
                h[gq] += dot8(w14[(size_t)(gq * 256 + t) * 32 + jj], ma, mb);
        }
        #pragma unroll
        for (int gq = 0; gq < 4; ++gq)
            lh1[gq * 256 + t] = fmaxf(h[gq] + b1[gq * 256 + t], 0.f);
    }
    __syncthreads();

    {
        const uint4* w24 = (const uint4*)w2_bf + (size_t)t * 128;
        const float4* h14 = (const float4*)lh1;
        float acc = 0.f;
        for (int kk = 0; kk < 128; ++kk)
            acc += dot8(w24[kk], h14[kk * 2], h14[kk * 2 + 1]);
        float res = smid + acc + b2[t];
        size_t o = ((size_t)b * 8 + qi) * 256 + t;
        slot[o] = res;
        if (out_slots) out_slots[o] = res;
    }
}

// ---------------------------------------------------------------------------
extern "C" void kernel_launch(void* const* d_in, const int* in_sizes, int n_in,
                              void* d_out, int out_size, void* d_ws, size_t ws_size,
                              hipStream_t stream) {
    const float* inp     = (const float*)d_in[0];
    const float* slots0  = (const float*)d_in[1];
    const float* ln_in_g = (const float*)d_in[2];
    const float* ln_in_b = (const float*)d_in[3];
    const float* ln_s_g  = (const float*)d_in[4];
    const float* ln_s_b  = (const float*)d_in[5];
    const float* ln_m_g  = (const float*)d_in[6];
    const float* ln_m_b  = (const float*)d_in[7];
    const float* Wq  = (const float*)d_in[8];
    const float* Wk  = (const float*)d_in[9];
    const float* Wv  = (const float*)d_in[10];
    const float* Wih = (const float*)d_in[11];
    const float* Whh = (const float*)d_in[12];
    const float* bih = (const float*)d_in[13];
    const float* bhh = (const float*)d_in[14];
    const float* W1  = (const float*)d_in[15];
    const float* b1  = (const float*)d_in[16];
    const float* W2  = (const float*)d_in[17];
    const float* b2  = (const float*)d_in[18];

    float* ws = (float*)d_ws;
    float* V_g  = ws + WS_V;
    float* A0_g = ws + WS_A0;
    float* A1_g = ws + WS_A1;
    float* c0_g = ws + WS_C0;
    float* c1_g = ws + WS_C1;
    float* slot = ws + WS_SLOT;
    unsigned short* wp_bf = (unsigned short*)(ws + WS_WPBF);
    unsigned short* bfbase = (unsigned short*)((char*)d_ws + WS_BF_BYTES);
    unsigned short* wih_bf = bfbase + BF_WIH;
    unsigned short* whh_bf = bfbase + BF_WHH;
    unsigned short* w1_bf  = bfbase + BF_W1;
    unsigned short* w2_bf  = bfbase + BF_W2;

    float* out_slots = (float*)d_out;
    float* out_vis   = out_slots + 32 * 8 * 256;
    float* out_temp  = out_vis + 32 * 4096 * 8;

    k_cvt<<<768, 256, 0, stream>>>(Wih, wih_bf, 196608);
    k_cvt<<<768, 256, 0, stream>>>(Whh, whh_bf, 196608);
    k_cvt<<<1024, 256, 0, stream>>>(W1, w1_bf, 262144);
    k_cvt<<<1024, 256, 0, stream>>>(W2, w2_bf, 262144);
    k_copy<<<256, 256, 0, stream>>>(slots0, slot, 65536);

    for (int it = 0; it < 3; ++it) {
        k_slotprep<<<32, 256, 0, stream>>>(slot, ln_s_g, ln_s_b, Wq, Wk,
                                           ln_in_g, ln_in_b, wp_bf, c0_g, c1_g,
                                           V_g, A0_g, A1_g);
        k_attn<<<dim3(32, 32), 256, 0, stream>>>(
            inp, wp_bf, c0_g, c1_g, V_g, A0_g, A1_g,
            out_vis, out_temp, (it == 2) ? 1 : 0);
        k_slotrow<<<256, 256, 0, stream>>>(
            V_g, A0_g, A1_g, ln_in_g, ln_in_b, Wv,
            wih_bf, whh_bf, bih, bhh, ln_m_g, ln_m_b, w1_bf, b1, w2_bf, b2,
            slot, (it == 2) ? out_slots : nullptr);
    }
}

// Round 4
// 551.177 us; speedup vs baseline: 2.1126x; 1.1121x over previous
//
#include <hip/hip_runtime.h>
#include <math.h>

// ---------------------------------------------------------------------------
// SlotAttention fused forward. MFMA (bf16) attention path.
// GRU/MLP chain as wide split kernels:
//   gx = yflat @ Wfold^T   (Wfold folds Wv into W_ih, precomputed once)
//   gh = slots @ Whh^T
//   smid = GRU(gx,gh,slots);  m = LN(smid);  h1 = relu(m@W1^T+b1)
//   slots' = smid + b2 + h1@W2^T   (split-K atomics into ping-pong slot buf)
// ---------------------------------------------------------------------------

#define NKV   4096
#define DD    256
#define HQN   32
#define EPSR  1e-8f

// workspace layout (float offsets)
#define WS_V      0                     // 262144 (aliased: h1 [256][1024] fp32)
#define WS_A0     262144                // 1024
#define WS_A1     263168                // 1024
#define WS_C0     264192                // 1024
#define WS_C1     265216                // 1024
#define WS_SLOTA  266240                // 65536
#define WS_SLOTB  331776                // 65536
#define WS_WPGXH  397312                // 393216 (wp_bf 131072f | gxh [256][1536])
#define WS_WFT    790528                // 393216 uints: WfoldT2 [512][768]
#define WS_WHHT   1183744               // 98304 uints:  WhhT2   [128][768]
#define WS_W1T    1282048               // 131072 uints: W1T2    [128][1024]
#define WS_W2T    1413120               // 131072 uints: W2T2    [512][256]
// total 1544192 floats = 6.18 MB (round-1 proved >=6.85 MB available)

typedef float f32x4 __attribute__((ext_vector_type(4)));
typedef short s16x8 __attribute__((ext_vector_type(8)));
typedef int   v2i   __attribute__((ext_vector_type(2)));

__device__ __forceinline__ unsigned bfr(float f) {
    unsigned u = __float_as_uint(f);
    return (u + 0x7fffu + ((u >> 16) & 1u)) >> 16;
}
__device__ __forceinline__ unsigned pk2(float lo, float hi) {
    return bfr(lo) | (bfr(hi) << 16);
}
__device__ __forceinline__ float bf2f(unsigned short us) {
    return __uint_as_float((unsigned)us << 16);
}
__device__ __forceinline__ float bflo(unsigned u) { return __uint_as_float(u << 16); }
__device__ __forceinline__ float bfhi(unsigned u) { return __uint_as_float(u & 0xffff0000u); }

__device__ __forceinline__ v2i tr_read(unsigned addr) {
    v2i d;
    asm volatile("ds_read_b64_tr_b16 %0, %1" : "=v"(d) : "v"(addr));
    return d;
}
__device__ __forceinline__ s16x8 mk_frag(v2i a, v2i b) {
    union { int i[4]; s16x8 s; } u;
    u.i[0] = a.x; u.i[1] = a.y; u.i[2] = b.x; u.i[3] = b.y;
    return u.s;
}

__global__ __launch_bounds__(256) void k_copy(const float* __restrict__ in,
                                              float* __restrict__ out, int n) {
    int i = blockIdx.x * 256 + threadIdx.x;
    if (i < n) out[i] = in[i];
}

// ---------------------------------------------------------------------------
// Wfold precompute: WfT2[k2][c] = pk2(Wfold[c][2k2], Wfold[c][2k2+1])
//   Wfold[c][h*256+j] = sum_d Wih[c][64h+d] * Wv[64h+d][j]
__global__ __launch_bounds__(256) void k_wfold(
    const float* __restrict__ Wih, const float* __restrict__ Wv,
    unsigned* __restrict__ WfT2)
{
    const int t = threadIdx.x;
    const int k2 = blockIdx.y;              // 512
    const int c = blockIdx.x * 256 + t;     // 3 chunks
    const int h = k2 >> 7;
    const int j0 = (k2 & 127) * 2;
    const float* wr = Wih + (size_t)c * 256 + h * 64;
    const float* vr = Wv + (size_t)(h * 64) * 256;
    float f0 = 0.f, f1 = 0.f;
    #pragma unroll 8
    for (int d = 0; d < 64; ++d) {
        float wv = wr[d];
        f0 = fmaf(wv, vr[d * 256 + j0], f0);
        f1 = fmaf(wv, vr[d * 256 + j0 + 1], f1);
    }
    WfT2[(size_t)k2 * 768 + c] = pk2(f0, f1);
}

// transpose+pack: in fp32 [R][C] -> out uint [C/2][R], out[c2*R+r]=pk2(in[r][2c2],in[r][2c2+1])
__global__ __launch_bounds__(256) void k_trpack(
    const float* __restrict__ in, unsigned* __restrict__ out, int R, int C)
{
    const int c2 = blockIdx.x;
    const int t = threadIdx.x;
    for (int q = 0; q < R / 256; ++q) {
        int r = q * 256 + t;
        out[(size_t)c2 * R + r] = pk2(in[(size_t)r * C + 2 * c2],
                                      in[(size_t)r * C + 2 * c2 + 1]);
    }
}

// ---------------------------------------------------------------------------
// Per-iteration slot prep (one block per batch).
__global__ __launch_bounds__(256) void k_slotprep(
    const float* __restrict__ slots, const float* __restrict__ g_s, const float* __restrict__ b_s,
    const float* __restrict__ Wq, const float* __restrict__ Wk,
    const float* __restrict__ g_in, const float* __restrict__ b_in,
    unsigned short* __restrict__ wp_bf, float* __restrict__ c0_g, float* __restrict__ c1_g,
    float* __restrict__ V_g, float* __restrict__ A0_g, float* __restrict__ A1_g)
{
    __shared__ float s_lds[2048];
    __shared__ float qf[2048];
    __shared__ float redc[2048];
    const int t = threadIdx.x;
    const int b = blockIdx.x;
    const int lane = t & 63, w = t >> 6;
    const float LNS = 0.125f * 1.44269504f;

    #pragma unroll
    for (int k = 0; k < 32; ++k) V_g[(size_t)b * 8192 + k * 256 + t] = 0.f;
    if (t < 32) { A0_g[b * 32 + t] = 0.f; A1_g[b * 32 + t] = 0.f; }

    // LN(slots)
    for (int r = w; r < 8; r += 4) {
        const float4 v = ((const float4*)(slots + ((size_t)b * 8 + r) * 256))[lane];
        float s0 = v.x + v.y + v.z + v.w;
        float s1 = v.x * v.x + v.y * v.y + v.z * v.z + v.w * v.w;
        #pragma unroll
        for (int o = 32; o >= 1; o >>= 1) { s0 += __shfl_xor(s0, o, 64); s1 += __shfl_xor(s1, o, 64); }
        float m = s0 * (1.f / 256.f);
        float rs = rsqrtf(s1 * (1.f / 256.f) - m * m + 1e-5f);
        float4 gg = ((const float4*)g_s)[lane];
        float4 bb = ((const float4*)b_s)[lane];
        float4 nn;
        nn.x = (v.x - m) * rs * gg.x + bb.x;
        nn.y = (v.y - m) * rs * gg.y + bb.y;
        nn.z = (v.z - m) * rs * gg.z + bb.z;
        nn.w = (v.w - m) * rs * gg.w + bb.w;
        ((float4*)(s_lds + r * 256))[lane] = nn;
    }
    __syncthreads();

    // qf[qi][e=t] = sum_j s[qi][j] * Wq[t][j]
    {
        float a[8];
        #pragma unroll
        for (int qi = 0; qi < 8; ++qi) a[qi] = 0.f;
        const float4* wq4 = (const float4*)Wq;
        for (int j4 = 0; j4 < 64; ++j4) {
            float4 wv = wq4[(size_t)t * 64 + j4];
            #pragma unroll
            for (int qi = 0; qi < 8; ++qi) {
                float4 sv = *(const float4*)(s_lds + qi * 256 + j4 * 4);
                a[qi] = fmaf(sv.x, wv.x, a[qi]);
                a[qi] = fmaf(sv.y, wv.y, a[qi]);
                a[qi] = fmaf(sv.z, wv.z, a[qi]);
                a[qi] = fmaf(sv.w, wv.w, a[qi]);
            }
        }
        #pragma unroll
        for (int qi = 0; qi < 8; ++qi) qf[qi * 256 + t] = a[qi];
    }
    __syncthreads();

    const float gv = g_in[t], bv = b_in[t];
    for (int h = 0; h < 4; ++h) {
        float a2[8];
        #pragma unroll
        for (int qi = 0; qi < 8; ++qi) a2[qi] = 0.f;
        for (int d = 0; d < 64; ++d) {
            float wv = Wk[(size_t)(h * 64 + d) * 256 + t];
            #pragma unroll
            for (int qi = 0; qi < 8; ++qi) a2[qi] = fmaf(qf[qi * 256 + h * 64 + d], wv, a2[qi]);
        }
        #pragma unroll
        for (int qi = 0; qi < 8; ++qi) {
            float kv = LNS * a2[qi];
            float we = kv * gv;
            wp_bf[((size_t)b * HQN + h * 8 + qi) * 256 + t] = (unsigned short)bfr(we);
            redc[qi * 256 + t] = we;
        }
        __syncthreads();
        #pragma unroll
        for (int rep = 0; rep < 2; ++rep) {
            int r = w * 2 + rep;
            float sv = redc[r * 256 + lane] + redc[r * 256 + 64 + lane] +
                       redc[r * 256 + 128 + lane] + redc[r * 256 + 192 + lane];
            #pragma unroll
            for (int o = 32; o >= 1; o >>= 1) sv += __shfl_xor(sv, o, 64);
            if (lane == 0) c1_g[b * 32 + h * 8 + r] = sv;
        }
        __syncthreads();
        #pragma unroll
        for (int qi = 0; qi < 8; ++qi) redc[qi * 256 + t] = LNS * a2[qi] * bv;
        __syncthreads();
        #pragma unroll
        for (int rep = 0; rep < 2; ++rep) {
            int r = w * 2 + rep;
            float sv = redc[r * 256 + lane] + redc[r * 256 + 64 + lane] +
                       redc[r * 256 + 128 + lane] + redc[r * 256 + 192 + lane];
            #pragma unroll
            for (int o = 32; o >= 1; o >>= 1) sv += __shfl_xor(sv, o, 64);
            if (lane == 0) c0_g[b * 32 + h * 8 + r] = sv;
        }
        __syncthreads();
    }
}

// ---------------------------------------------------------------------------
// Main fused MFMA pass (unchanged from round 3).
__global__ __launch_bounds__(256, 4) void k_attn(
    const float* __restrict__ inp, const unsigned short* __restrict__ wp_bf,
    const float* __restrict__ c0_g, const float* __restrict__ c1_g,
    float* __restrict__ V_g, float* __restrict__ A0_g, float* __restrict__ A1_g,
    float* __restrict__ out_vis, float* __restrict__ out_temp, int write_vis)
{
    __shared__ unsigned short xb[16 * 520];
    __shared__ unsigned short wl[8192];
    __shared__ unsigned short pt[1024];
    __shared__ float stats[32];
    __shared__ float redm[64];
    __shared__ float reds[64];

    const int t = threadIdx.x;
    const int l = t & 63, w = t >> 6;
    const int g = l >> 4, li = l & 15;
    const int b = blockIdx.y, kb = blockIdx.x;

    char* xbB = (char*)xb;
    char* wlB = (char*)wl;
    char* ptB = (char*)pt;

    const int tok_s = t >> 3, seg8 = t & 7;

    {
        const uint4* wp4 = (const uint4*)wp_bf + ((size_t)b * 8192 + (t >> 3) * 256 + (t & 7) * 32) / 8;
        const int hq = t >> 3, sg = t & 7;
        #pragma unroll
        for (int q = 0; q < 4; ++q) {
            uint4 v = wp4[q];
            *(uint4*)(wlB + hq * 512 + (((sg * 4 + q) ^ (hq & 7)) * 16)) = v;
        }
    }

    const int Mt = w & 1, Nt = w >> 1;
    const int hqB = Nt * 16 + li;
    const float c0r = c0_g[b * 32 + hqB];
    const float c1r = c1_g[b * 32 + hqB];
    const int MtV = w >> 1, ntb = (w & 1) * 8;
    const int hqA = MtV * 16 + li;

    f32x4 av[8];
    #pragma unroll
    for (int u = 0; u < 8; ++u) av[u] = (f32x4){0.f, 0.f, 0.f, 0.f};
    float A0acc = 0.f, A1acc = 0.f;

    const unsigned xbase = (unsigned)(uintptr_t)xbB;

    for (int ci = 0; ci < 4; ++ci) {
        const int n0 = (kb * 4 + ci) * 32;

        const float4* row4 = (const float4*)(inp + ((size_t)b * NKV + n0 + tok_s) * 256);
        float4 ld[8];
        #pragma unroll
        for (int c = 0; c < 2; ++c)
            #pragma unroll
            for (int q = 0; q < 4; ++q)
                ld[c * 4 + q] = row4[c * 32 + seg8 * 4 + q];
        float s0 = 0.f, s1 = 0.f;
        #pragma unroll
        for (int u = 0; u < 8; ++u) {
            float4 v = ld[u];
            s0 += v.x + v.y + v.z + v.w;
            s1 = fmaf(v.x, v.x, s1); s1 = fmaf(v.y, v.y, s1);
            s1 = fmaf(v.z, v.z, s1); s1 = fmaf(v.w, v.w, s1);
        }
        s0 += __shfl_xor(s0, 1, 64); s1 += __shfl_xor(s1, 1, 64);
        s0 += __shfl_xor(s0, 2, 64); s1 += __shfl_xor(s1, 2, 64);
        s0 += __shfl_xor(s0, 4, 64); s1 += __shfl_xor(s1, 4, 64);
        float m  = s0 * (1.f / 256.f);
        float rs = rsqrtf(s1 * (1.f / 256.f) - m * m + 1e-5f);
        if (seg8 == 0) stats[tok_s] = rs * m;
        #pragma unroll
        for (int c = 0; c < 2; ++c) {
            int nt = seg8 + 8 * c;
            #pragma unroll
            for (int h = 0; h < 2; ++h) {
                float4 fa = ld[c * 4 + h * 2], fb = ld[c * 4 + h * 2 + 1];
                uint4 pk;
                pk.x = pk2(rs * fa.x, rs * fa.y); pk.y = pk2(rs * fa.z, rs * fa.w);
                pk.z = pk2(rs * fb.x, rs * fb.y); pk.w = pk2(rs * fb.z, rs * fb.w);
                *(uint4*)(xbB + nt * 1040 + tok_s * 32 + h * 16) = pk;
            }
        }
        __syncthreads();

        f32x4 accS = (f32x4){0.f, 0.f, 0.f, 0.f};
        #pragma unroll
        for (int kk = 0; kk < 8; ++kk) {
            s16x8 af = *(const s16x8*)(xbB + (kk * 2 + (g >> 1)) * 1040 +
                                       (Mt * 16 + li) * 32 + (g & 1) * 16);
            s16x8 bf = *(const s16x8*)(wlB + hqB * 512 + (((kk * 4 + g) ^ (hqB & 7)) * 16));
            accS = __builtin_amdgcn_mfma_f32_16x16x32_bf16(af, bf, accS, 0, 0, 0);
        }

        float lg[4], rmv[4], ex[4], aa[4];
        #pragma unroll
        for (int r = 0; r < 4; ++r) {
            rmv[r] = stats[Mt * 16 + g * 4 + r];
            lg[r] = accS[r] - rmv[r] * c1r + c0r;
        }
        #pragma unroll
        for (int r = 0; r < 4; ++r) {
            float v = lg[r];
            v = fmaxf(v, __shfl_xor(v, 1, 64));
            v = fmaxf(v, __shfl_xor(v, 2, 64));
            v = fmaxf(v, __shfl_xor(v, 4, 64));
            v = fmaxf(v, __shfl_xor(v, 8, 64));
            if (li == 0) redm[(Mt * 16 + g * 4 + r) * 2 + Nt] = v;
        }
        __syncthreads();
        #pragma unroll
        for (int r = 0; r < 4; ++r) {
            int tokr = Mt * 16 + g * 4 + r;
            float mx = fmaxf(redm[tokr * 2], redm[tokr * 2 + 1]);
            ex[r] = exp2f(lg[r] - mx);
            float v = ex[r];
            v += __shfl_xor(v, 1, 64);
            v += __shfl_xor(v, 2, 64);
            v += __shfl_xor(v, 4, 64);
            v += __shfl_xor(v, 8, 64);
            if (li == 0) reds[tokr * 2 + Nt] = v;
        }
        __syncthreads();
        #pragma unroll
        for (int r = 0; r < 4; ++r) {
            int tokr = Mt * 16 + g * 4 + r;
            float tot = reds[tokr * 2] + reds[tokr * 2 + 1];
            aa[r] = ex[r] / tot;
            A0acc += aa[r];
            A1acc = fmaf(aa[r], rmv[r], A1acc);
        }
        {
            uint2 pw;
            pw.x = pk2(aa[0], aa[1]);
            pw.y = pk2(aa[2], aa[3]);
            int tokb = Mt * 16 + g * 4;
            int slot = (tokb >> 3) ^ ((hqB >> 1) & 3);
            *(uint2*)(ptB + hqB * 64 + slot * 16 + (tokb & 7) * 2) = pw;
        }
        __syncthreads();

        if (write_vis) {
            int tk = t >> 3, q = t & 7;
            float sv = 0.f;
            #pragma unroll
            for (int h = 0; h < 4; ++h) {
                int hq = h * 8 + q;
                int slot = (tk >> 3) ^ ((hq >> 1) & 3);
                sv += bf2f(*(const unsigned short*)(ptB + hq * 64 + slot * 16 + (tk & 7) * 2));
            }
            size_t o = ((size_t)b * NKV + n0 + tk) * 8 + q;
            out_vis[o] = sv; out_temp[o] = sv;
        }

        {
            s16x8 pa = *(const s16x8*)(ptB + hqA * 64 + ((g ^ ((hqA >> 1) & 3)) * 16));
            unsigned abase = xbase + g * 256 + li * 8;
            v2i t0a = tr_read(abase + (ntb + 0) * 1040);
            v2i t0b = tr_read(abase + (ntb + 0) * 1040 + 128);
            v2i t1a = tr_read(abase + (ntb + 1) * 1040);
            v2i t1b = tr_read(abase + (ntb + 1) * 1040 + 128);
            v2i t2a = tr_read(abase + (ntb + 2) * 1040);
            v2i t2b = tr_read(abase + (ntb + 2) * 1040 + 128);
            v2i t3a = tr_read(abase + (ntb + 3) * 1040);
            v2i t3b = tr_read(abase + (ntb + 3) * 1040 + 128);
            asm volatile("s_waitcnt lgkmcnt(0)" ::: "memory");
            __builtin_amdgcn_sched_barrier(0);
            av[0] = __builtin_amdgcn_mfma_f32_16x16x32_bf16(pa, mk_frag(t0a, t0b), av[0], 0, 0, 0);
            av[1] = __builtin_amdgcn_mfma_f32_16x16x32_bf16(pa, mk_frag(t1a, t1b), av[1], 0, 0, 0);
            av[2] = __builtin_amdgcn_mfma_f32_16x16x32_bf16(pa, mk_frag(t2a, t2b), av[2], 0, 0, 0);
            av[3] = __builtin_amdgcn_mfma_f32_16x16x32_bf16(pa, mk_frag(t3a, t3b), av[3], 0, 0, 0);
            v2i t4a = tr_read(abase + (ntb + 4) * 1040);
            v2i t4b = tr_read(abase + (ntb + 4) * 1040 + 128);
            v2i t5a = tr_read(abase + (ntb + 5) * 1040);
            v2i t5b = tr_read(abase + (ntb + 5) * 1040 + 128);
            v2i t6a = tr_read(abase + (ntb + 6) * 1040);
            v2i t6b = tr_read(abase + (ntb + 6) * 1040 + 128);
            v2i t7a = tr_read(abase + (ntb + 7) * 1040);
            v2i t7b = tr_read(abase + (ntb + 7) * 1040 + 128);
            asm volatile("s_waitcnt lgkmcnt(0)" ::: "memory");
            __builtin_amdgcn_sched_barrier(0);
            av[4] = __builtin_amdgcn_mfma_f32_16x16x32_bf16(pa, mk_frag(t4a, t4b), av[4], 0, 0, 0);
            av[5] = __builtin_amdgcn_mfma_f32_16x16x32_bf16(pa, mk_frag(t5a, t5b), av[5], 0, 0, 0);
            av[6] = __builtin_amdgcn_mfma_f32_16x16x32_bf16(pa, mk_frag(t6a, t6b), av[6], 0, 0, 0);
            av[7] = __builtin_amdgcn_mfma_f32_16x16x32_bf16(pa, mk_frag(t7a, t7b), av[7], 0, 0, 0);
        }
        __syncthreads();
    }

    A0acc += __shfl_xor(A0acc, 16, 64); A0acc += __shfl_xor(A0acc, 32, 64);
    A1acc += __shfl_xor(A1acc, 16, 64); A1acc += __shfl_xor(A1acc, 32, 64);
    if (g == 0) {
        atomicAdd(A0_g + b * 32 + hqB, A0acc);
        atomicAdd(A1_g + b * 32 + hqB, A1acc);
    }
    #pragma unroll
    for (int i = 0; i < 8; ++i) {
        int j = (ntb + i) * 16 + li;
        #pragma unroll
        for (int r = 0; r < 4; ++r) {
            int hq = MtV * 16 + g * 4 + r;
            atomicAdd(V_g + ((size_t)b * 32 + hq) * 256 + j, av[i][r]);
        }
    }
}

// ---------------------------------------------------------------------------
// gx | gh GEMMs. grid (6, 64): y=rg (4 rows), x=chunk (0-2: gx, 3-5: gh).
__global__ __launch_bounds__(256) void k_gates(
    const float* __restrict__ V_g, const float* __restrict__ A0_g,
    const float* __restrict__ A1_g,
    const float* __restrict__ g_in, const float* __restrict__ b_in,
    const float* __restrict__ slot_cur,
    const unsigned* __restrict__ WfT2, const unsigned* __restrict__ WhhT2,
    float* __restrict__ gxh)
{
    __shared__ __align__(16) float aT[1024 * 4];   // [k][rr]
    const int t = threadIdx.x;
    const int rg = blockIdx.y;
    const int chunk = blockIdx.x;
    const int row0 = rg * 4;
    float acc0 = 0.f, acc1 = 0.f, acc2 = 0.f, acc3 = 0.f;

    if (chunk < 3) {
        const int b = rg >> 1, qi0 = (rg & 1) * 4;
        const float gt = g_in[t], bt = b_in[t];
        #pragma unroll
        for (int kk = 0; kk < 4; ++kk) {
            float4 y4;
            #pragma unroll
            for (int rr = 0; rr < 4; ++rr) {
                int hq = kk * 8 + qi0 + rr;
                float A0 = A0_g[b * 32 + hq], A1 = A1_g[b * 32 + hq];
                float den = A0 + EPSR * (float)NKV;
                float vv = V_g[((size_t)b * 32 + hq) * 256 + t];
                float yv = (gt * (vv - A1) + bt * A0) / den;
                ((float*)&y4)[rr] = yv;
            }
            *(float4*)(aT + (kk * 256 + t) * 4) = y4;
        }
        __syncthreads();
        const unsigned* wp = WfT2 + chunk * 256 + t;
        #pragma unroll 4
        for (int k2 = 0; k2 < 512; ++k2) {
            unsigned wv = wp[(size_t)k2 * 768];
            float w0 = bflo(wv), w1 = bfhi(wv);
            float4 a0 = *(const float4*)(aT + 8 * k2);
            float4 a1 = *(const float4*)(aT + 8 * k2 + 4);
            acc0 = fmaf(a0.x, w0, acc0); acc0 = fmaf(a1.x, w1, acc0);
            acc1 = fmaf(a0.y, w0, acc1); acc1 = fmaf(a1.y, w1, acc1);
            acc2 = fmaf(a0.z, w0, acc2); acc2 = fmaf(a1.z, w1, acc2);
            acc3 = fmaf(a0.w, w0, acc3); acc3 = fmaf(a1.w, w1, acc3);
        }
        float* go = gxh + (size_t)row0 * 1536 + chunk * 256 + t;
        go[0] = acc0; go[1536] = acc1; go[3072] = acc2; go[4608] = acc3;
    } else {
        const int gc = chunk - 3;
        {
            float4 y4;
            #pragma unroll
            for (int rr = 0; rr < 4; ++rr)
                ((float*)&y4)[rr] = slot_cur[(size_t)(row0 + rr) * 256 + t];
            *(float4*)(aT + t * 4) = y4;
        }
        __syncthreads();
        const unsigned* wp = WhhT2 + gc * 256 + t;
        #pragma unroll 4
        for (int k2 = 0; k2 < 128; ++k2) {
            unsigned wv = wp[(size_t)k2 * 768];
            float w0 = bflo(wv), w1 = bfhi(wv);
            float4 a0 = *(const float4*)(aT + 8 * k2);
            float4 a1 = *(const float4*)(aT + 8 * k2 + 4);
            acc0 = fmaf(a0.x, w0, acc0); acc0 = fmaf(a1.x, w1, acc0);
            acc1 = fmaf(a0.y, w0, acc1); acc1 = fmaf(a1.y, w1, acc1);
            acc2 = fmaf(a0.z, w0, acc2); acc2 = fmaf(a1.z, w1, acc2);
            acc3 = fmaf(a0.w, w0, acc3); acc3 = fmaf(a1.w, w1, acc3);
        }
        float* go = gxh + (size_t)row0 * 1536 + 768 + gc * 256 + t;
        go[0] = acc0; go[1536] = acc1; go[3072] = acc2; go[4608] = acc3;
    }
}

// ---------------------------------------------------------------------------
// GRU elementwise + LN head, then m @ W1^T + relu. grid (4, 64).
// chunk 0 also writes slot_nxt = smid + b2 (base for mlp2 atomics).
__global__ __launch_bounds__(256) void k_mlp1(
    const float* __restrict__ gxh, const float* __restrict__ slot_cur,
    const float* __restrict__ bih, const float* __restrict__ bhh,
    const float* __restrict__ gm, const float* __restrict__ bm,
    const unsigned* __restrict__ W1T2, const float* __restrict__ b1,
    const float* __restrict__ b2,
    float* __restrict__ slot_nxt, float* __restrict__ h1)
{
    __shared__ __align__(16) float mT[256 * 4];
    __shared__ float sm_l[4][256];
    __shared__ float lnst[8];
    const int t = threadIdx.x;
    const int rg = blockIdx.y, chunk = blockIdx.x;
    const int row0 = rg * 4;
    const int lane = t & 63, w = t >> 6;

    const float bi0 = bih[t], bi1 = bih[256 + t], bi2 = bih[512 + t];
    const float bh0 = bhh[t], bh1 = bhh[256 + t], bh2 = bhh[512 + t];
    float smid[4];
    #pragma unroll
    for (int rr = 0; rr < 4; ++rr) {
        const float* gr = gxh + (size_t)(row0 + rr) * 1536;
        float gx0 = gr[t], gx1 = gr[256 + t], gx2 = gr[512 + t];
        float gh0 = gr[768 + t], gh1 = gr[1024 + t], gh2 = gr[1280 + t];
        float spv = slot_cur[(size_t)(row0 + rr) * 256 + t];
        float r = 1.f / (1.f + __expf(-(gx0 + bi0 + gh0 + bh0)));
        float z = 1.f / (1.f + __expf(-(gx1 + bi1 + gh1 + bh1)));
        float n = tanhf(gx2 + bi2 + r * (gh2 + bh2));
        smid[rr] = (1.f - z) * n + z * spv;
        sm_l[rr][t] = smid[rr];
    }
    __syncthreads();
    {
        float4 v = *(const float4*)(&sm_l[w][lane * 4]);
        float s0 = v.x + v.y + v.z + v.w;
        float s1 = v.x * v.x + v.y * v.y + v.z * v.z + v.w * v.w;
        #pragma unroll
        for (int o = 32; o >= 1; o >>= 1) { s0 += __shfl_xor(s0, o, 64); s1 += __shfl_xor(s1, o, 64); }
        if (lane == 0) {
            float mu = s0 * (1.f / 256.f);
            lnst[w * 2] = mu;
            lnst[w * 2 + 1] = rsqrtf(s1 * (1.f / 256.f) - mu * mu + 1e-5f);
        }
    }
    __syncthreads();
    {
        const float gmt = gm[t], bmt = bm[t];
        float4 m4;
        #pragma unroll
        for (int rr = 0; rr < 4; ++rr)
            ((float*)&m4)[rr] = (smid[rr] - lnst[rr * 2]) * lnst[rr * 2 + 1] * gmt + bmt;
        *(float4*)(mT + t * 4) = m4;
        if (chunk == 0) {
            const float b2t = b2[t];
            #pragma unroll
            for (int rr = 0; rr < 4; ++rr)
                slot_nxt[(size_t)(row0 + rr) * 256 + t] = smid[rr] + b2t;
        }
    }
    __syncthreads();

    float acc0 = 0.f, acc1 = 0.f, acc2 = 0.f, acc3 = 0.f;
    const unsigned* wp = W1T2 + chunk * 256 + t;
    #pragma unroll 4
    for (int k2 = 0; k2 < 128; ++k2) {
        unsigned wv = wp[(size_t)k2 * 1024];
        float w0 = bflo(wv), w1 = bfhi(wv);
        float4 a0 = *(const float4*)(mT + 8 * k2);
        float4 a1 = *(const float4*)(mT + 8 * k2 + 4);
        acc0 = fmaf(a0.x, w0, acc0); acc0 = fmaf(a1.x, w1, acc0);
        acc1 = fmaf(a0.y, w0, acc1); acc1 = fmaf(a1.y, w1, acc1);
        acc2 = fmaf(a0.z, w0, acc2); acc2 = fmaf(a1.z, w1, acc2);
        acc3 = fmaf(a0.w, w0, acc3); acc3 = fmaf(a1.w, w1, acc3);
    }
    const float b1t = b1[chunk * 256 + t];
    float* ho = h1 + (size_t)row0 * 1024 + chunk * 256 + t;
    ho[0]    = fmaxf(acc0 + b1t, 0.f);
    ho[1024] = fmaxf(acc1 + b1t, 0.f);
    ho[2048] = fmaxf(acc2 + b1t, 0.f);
    ho[3072] = fmaxf(acc3 + b1t, 0.f);
}

// ---------------------------------------------------------------------------
// h1 @ W2^T, 4-way split-K, atomicAdd into slot_nxt. grid (4, 64).
__global__ __launch_bounds__(256) void k_mlp2(
    const float* __restrict__ h1, const unsigned* __restrict__ W2T2,
    float* __restrict__ slot_nxt)
{
    __shared__ __align__(16) float hT[256 * 4];
    const int t = threadIdx.x;
    const int ks = blockIdx.x, rg = blockIdx.y;
    const int row0 = rg * 4;
    {
        float4 y4;
        #pragma unroll
        for (int rr = 0; rr < 4; ++rr)
            ((float*)&y4)[rr] = h1[(size_t)(row0 + rr) * 1024 + ks * 256 + t];
        *(float4*)(hT + t * 4) = y4;
    }
    __syncthreads();
    float acc0 = 0.f, acc1 = 0.f, acc2 = 0.f, acc3 = 0.f;
    const unsigned* wp = W2T2 + (size_t)(ks * 128) * 256 + t;
    #pragma unroll 4
    for (int k2 = 0; k2 < 128; ++k2) {
        unsigned wv = wp[(size_t)k2 * 256];
        float w0 = bflo(wv), w1 = bfhi(wv);
        float4 a0 = *(const float4*)(hT + 8 * k2);
        float4 a1 = *(const float4*)(hT + 8 * k2 + 4);
        acc0 = fmaf(a0.x, w0, acc0); acc0 = fmaf(a1.x, w1, acc0);
        acc1 = fmaf(a0.y, w0, acc1); acc1 = fmaf(a1.y, w1, acc1);
        acc2 = fmaf(a0.z, w0, acc2); acc2 = fmaf(a1.z, w1, acc2);
        acc3 = fmaf(a0.w, w0, acc3); acc3 = fmaf(a1.w, w1, acc3);
    }
    atomicAdd(slot_nxt + (size_t)(row0 + 0) * 256 + t, acc0);
    atomicAdd(slot_nxt + (size_t)(row0 + 1) * 256 + t, acc1);
    atomicAdd(slot_nxt + (size_t)(row0 + 2) * 256 + t, acc2);
    atomicAdd(slot_nxt + (size_t)(row0 + 3) * 256 + t, acc3);
}

// ---------------------------------------------------------------------------
extern "C" void kernel_launch(void* const* d_in, const int* in_sizes, int n_in,
                              void* d_out, int out_size, void* d_ws, size_t ws_size,
                              hipStream_t stream) {
    const float* inp     = (const float*)d_in[0];
    const float* slots0  = (const float*)d_in[1];
    const float* ln_in_g = (const float*)d_in[2];
    const float* ln_in_b = (const float*)d_in[3];
    const float* ln_s_g  = (const float*)d_in[4];
    const float* ln_s_b  = (const float*)d_in[5];
    const float* ln_m_g  = (const float*)d_in[6];
    const float* ln_m_b  = (const float*)d_in[7];
    const float* Wq  = (const float*)d_in[8];
    const float* Wk  = (const float*)d_in[9];
    const float* Wv  = (const float*)d_in[10];
    const float* Wih = (const float*)d_in[11];
    const float* Whh = (const float*)d_in[12];
    const float* bih = (const float*)d_in[13];
    const float* bhh = (const float*)d_in[14];
    const float* W1  = (const float*)d_in[15];
    const float* b1  = (const float*)d_in[16];
    const float* W2  = (const float*)d_in[17];
    const float* b2  = (const float*)d_in[18];

    float* ws = (float*)d_ws;
    float* V_g   = ws + WS_V;        // aliased with h1
    float* h1    = ws + WS_V;
    float* A0_g  = ws + WS_A0;
    float* A1_g  = ws + WS_A1;
    float* c0_g  = ws + WS_C0;
    float* c1_g  = ws + WS_C1;
    float* slotA = ws + WS_SLOTA;
    float* slotB = ws + WS_SLOTB;
    float* gxh   = ws + WS_WPGXH;    // aliased with wp_bf
    unsigned short* wp_bf = (unsigned short*)(ws + WS_WPGXH);
    unsigned* WfT2  = (unsigned*)(ws + WS_WFT);
    unsigned* WhhT2 = (unsigned*)(ws + WS_WHHT);
    unsigned* W1T2  = (unsigned*)(ws + WS_W1T);
    unsigned* W2T2  = (unsigned*)(ws + WS_W2T);

    float* out_slots = (float*)d_out;
    float* out_vis   = out_slots + 32 * 8 * 256;
    float* out_temp  = out_vis + 32 * 4096 * 8;

    k_wfold<<<dim3(3, 512), 256, 0, stream>>>(Wih, Wv, WfT2);
    k_trpack<<<128, 256, 0, stream>>>(Whh, WhhT2, 768, 256);
    k_trpack<<<128, 256, 0, stream>>>(W1, W1T2, 1024, 256);
    k_trpack<<<512, 256, 0, stream>>>(W2, W2T2, 256, 1024);
    k_copy<<<256, 256, 0, stream>>>(slots0, slotA, 65536);

    for (int it = 0; it < 3; ++it) {
        float* cur = (it & 1) ? slotB : slotA;
        float* nxt = (it & 1) ? slotA : slotB;
        k_slotprep<<<32, 256, 0, stream>>>(cur, ln_s_g, ln_s_b, Wq, Wk,
                                           ln_in_g, ln_in_b, wp_bf, c0_g, c1_g,
                                           V_g, A0_g, A1_g);
        k_attn<<<dim3(32, 32), 256, 0, stream>>>(
            inp, wp_bf, c0_g, c1_g, V_g, A0_g, A1_g,
            out_vis, out_temp, (it == 2) ? 1 : 0);
        k_gates<<<dim3(6, 64), 256, 0, stream>>>(
            V_g, A0_g, A1_g, ln_in_g, ln_in_b, cur, WfT2, WhhT2, gxh);
        k_mlp1<<<dim3(4, 64), 256, 0, stream>>>(
            gxh, cur, bih, bhh, ln_m_g, ln_m_b, W1T2, b1, b2, nxt, h1);
        k_mlp2<<<dim3(4, 64), 256, 0, stream>>>(h1, W2T2, nxt);
    }
    k_copy<<<256, 256, 0, stream>>>(slotB, out_slots, 65536);
}